// Round 6
// baseline (5749.485 us; speedup 1.0000x reference)
//
#include <hip/hip_runtime.h>
#include <math.h>

#define B_ 64
#define M_ 1024
#define H_ 64
#define N_ (B_*M_)   // 65536

typedef _Float16 half8 __attribute__((ext_vector_type(8)));
typedef float  floatx4 __attribute__((ext_vector_type(4)));

#define MFMA16(a,b,c) __builtin_amdgcn_mfma_f32_16x16x32_f16(a,b,c,0,0,0)
#define MED3(a,b,c)   __builtin_amdgcn_fmed3f(a,b,c)

// ---------------- encoder: h = relu(relu(x@w1+b1)@w2+b2) (+ f16 split + sq) ------
__global__ __launch_bounds__(256) void enc_kernel(
    const float* __restrict__ x,     // [N,4]
    const float* __restrict__ w1,    // [4,32]
    const float* __restrict__ b1,    // [32]
    const float* __restrict__ w2,    // [32,64]
    const float* __restrict__ b2,    // [64]
    float* __restrict__ h,           // [N,64]
    _Float16* __restrict__ hhi,      // [N,64]
    _Float16* __restrict__ hlo,      // [N,64]
    float* __restrict__ sq)          // [N]
{
    __shared__ float sw1[4*32];
    __shared__ float sb1[32];
    __shared__ float sw2[32*64];
    __shared__ float sb2[64];
    int t = threadIdx.x;
    for (int i = t; i < 128; i += 256) sw1[i] = w1[i];
    if (t < 32) sb1[t] = b1[t];
    for (int i = t; i < 2048; i += 256) sw2[i] = w2[i];
    if (t < 64) sb2[t] = b2[t];
    __syncthreads();
    int n = blockIdx.x * 256 + t;
    float4 xv = *(const float4*)(x + (size_t)n*4);
    float hid[32];
    #pragma unroll
    for (int o = 0; o < 32; ++o) {
        float a = sb1[o] + xv.x*sw1[0*32+o] + xv.y*sw1[1*32+o]
                        + xv.z*sw1[2*32+o] + xv.w*sw1[3*32+o];
        hid[o] = fmaxf(a, 0.f);
    }
    float* hout = h + (size_t)n*64;
    float sqa = 0.f;
    #pragma unroll 4
    for (int oc = 0; oc < 16; ++oc) {
        float4 acc = make_float4(sb2[oc*4+0], sb2[oc*4+1], sb2[oc*4+2], sb2[oc*4+3]);
        #pragma unroll
        for (int f = 0; f < 32; ++f) {
            float4 w = *(const float4*)(sw2 + f*64 + oc*4);
            float hv = hid[f];
            acc.x += hv*w.x; acc.y += hv*w.y; acc.z += hv*w.z; acc.w += hv*w.w;
        }
        acc.x = fmaxf(acc.x,0.f); acc.y = fmaxf(acc.y,0.f);
        acc.z = fmaxf(acc.z,0.f); acc.w = fmaxf(acc.w,0.f);
        *(float4*)(hout + oc*4) = acc;
        sqa += acc.x*acc.x + acc.y*acc.y + acc.z*acc.z + acc.w*acc.w;
        union { _Float16 f[4]; uint2 u; } Hh, Hl;
        Hh.f[0]=(_Float16)acc.x; Hh.f[1]=(_Float16)acc.y;
        Hh.f[2]=(_Float16)acc.z; Hh.f[3]=(_Float16)acc.w;
        Hl.f[0]=(_Float16)(acc.x-(float)Hh.f[0]); Hl.f[1]=(_Float16)(acc.y-(float)Hh.f[1]);
        Hl.f[2]=(_Float16)(acc.z-(float)Hh.f[2]); Hl.f[3]=(_Float16)(acc.w-(float)Hh.f[3]);
        *(uint2*)(hhi + (size_t)n*64 + oc*4) = Hh.u;
        *(uint2*)(hlo + (size_t)n*64 + oc*4) = Hl.u;
    }
    sq[n] = sqa;
}

// ---------------- convert: h -> (hhi, hlo, sq)  (after edge layer 1) -------------
__global__ __launch_bounds__(256) void convert_kernel(
    const float* __restrict__ h,
    _Float16* __restrict__ hhi, _Float16* __restrict__ hlo,
    float* __restrict__ sq)
{
    int t = threadIdx.x, lane = t & 63, w = t >> 6;
    int base = blockIdx.x * 64 + w * 16;
    for (int it = 0; it < 16; ++it) {
        int i = base + it;
        float v = h[(size_t)i*64 + lane];
        _Float16 hi = (_Float16)v;
        _Float16 lo = (_Float16)(v - (float)hi);
        hhi[(size_t)i*64 + lane] = hi;
        hlo[(size_t)i*64 + lane] = lo;
        float s = v*v;
        #pragma unroll
        for (int off = 1; off < 64; off <<= 1) s += __shfl_xor(s, off, 64);
        if (lane == 0) sq[i] = s;
    }
}

// ---------------- A = h @ W1b  (W1b = rows 64..127 of w1) ----------------
__global__ __launch_bounds__(256) void gemmA_kernel(
    const float* __restrict__ h,
    const float* __restrict__ w1,   // [128,64]
    float* __restrict__ A)
{
    __shared__ float sw[64*64];
    int t = threadIdx.x;
    for (int idx = t; idx < 4096; idx += 256) sw[idx] = w1[4096 + idx];
    __syncthreads();
    int n = blockIdx.x * 256 + t;
    float4 hv[16];
    const float* src = h + (size_t)n*64;
    #pragma unroll
    for (int c = 0; c < 16; ++c) hv[c] = *(const float4*)(src + c*4);
    float* dst = A + (size_t)n*64;
    #pragma unroll 2
    for (int oc = 0; oc < 16; ++oc) {
        float4 acc = make_float4(0.f,0.f,0.f,0.f);
        #pragma unroll
        for (int f = 0; f < 64; ++f) {
            float xv = ((const float*)hv)[f];
            float4 w = *(const float4*)(sw + f*64 + oc*4);
            acc.x += xv*w.x; acc.y += xv*w.y; acc.z += xv*w.z; acc.w += xv*w.w;
        }
        *(float4*)(dst + oc*4) = acc;
    }
}

// ---------------- kNN v5: v4 structure, NO occupancy cap (R5's cap caused spills) -
// block = 64 queries x 1024 candidates; 4 waves split candidates (256 each).
// Rank score s = sq_j - 2*dot(h_i,h_j); dot via f16 split (hi*hi+hi*lo+lo*hi).
// Pass 0: med3-network top-16 values -> exact tau. Pass 1: recompute (bit-identical)
// and collect indices with s < tau, tie-fill s == tau.
__global__ __launch_bounds__(256) void knn_kernel(
    const _Float16* __restrict__ hhi,
    const _Float16* __restrict__ hlo,
    const float* __restrict__ sqg,
    unsigned short* __restrict__ knn)    // [N,16]
{
    __shared__ float D[4][64*17];         // per-wave 64q x 16c tile, stride 17
    __shared__ unsigned int cntL[64], cntE[64];
    __shared__ unsigned short eqbuf[64][16];
    int t = threadIdx.x, lane = t & 63, w = t >> 6;
    int bi = blockIdx.x;
    int g  = (bi & 7) | ((bi >> 7) << 3);  // all 16 blocks of a graph share bi%8 -> same XCD L2
    int qt = (bi >> 3) & 15;
    const _Float16* hhig = hhi + (size_t)g*M_*64;
    const _Float16* hlog = hlo + (size_t)g*M_*64;
    const float*    sqb  = sqg + (size_t)g*M_;
    if (t < 64) { cntL[t] = 0; cntE[t] = 0; }

    // A fragments (queries): lane holds A[m=lane&15][k=(lane>>4)*8 + j]
    int m16  = lane & 15;
    int koct = (lane >> 4) * 8;
    half8 Ahi[4][2], Alo[4][2];
    #pragma unroll
    for (int rb = 0; rb < 4; ++rb) {
        const _Float16* ph = hhig + (size_t)(qt*64 + rb*16 + m16)*64;
        const _Float16* pl = hlog + (size_t)(qt*64 + rb*16 + m16)*64;
        Ahi[rb][0] = *(const half8*)(ph + koct);
        Ahi[rb][1] = *(const half8*)(ph + 32 + koct);
        Alo[rb][0] = *(const half8*)(pl + koct);
        Alo[rb][1] = *(const half8*)(pl + 32 + koct);
    }
    float* Dw   = D[w];
    int    crow = (lane >> 4) * 4;   // C/D: col=lane&15, row=(lane>>4)*4+reg
    float  bd[16];
    #pragma unroll
    for (int k = 0; k < 16; ++k) bd[k] = INFINITY;
    float tau = 0.f;
    size_t gq = (size_t)g*M_ + qt*64 + lane;
    int cand0 = w*256;               // this wave's candidate range base

    for (int pass = 0; pass < 2; ++pass) {
        half8 Bh[2][2], Bl[2][2];
        {   // prefetch sub-tile 0
            const _Float16* ph = hhig + (size_t)(cand0 + m16)*64;
            const _Float16* pl = hlog + (size_t)(cand0 + m16)*64;
            Bh[0][0] = *(const half8*)(ph + koct);
            Bh[0][1] = *(const half8*)(ph + 32 + koct);
            Bl[0][0] = *(const half8*)(pl + koct);
            Bl[0][1] = *(const half8*)(pl + 32 + koct);
        }
        for (int st = 0; st < 16; ++st) {
            int cur = st & 1, nxt = cur ^ 1;
            if (st < 15) {           // prefetch next sub-tile's B fragments
                int cb0 = cand0 + (st+1)*16;
                const _Float16* ph = hhig + (size_t)(cb0 + m16)*64;
                const _Float16* pl = hlog + (size_t)(cb0 + m16)*64;
                Bh[nxt][0] = *(const half8*)(ph + koct);
                Bh[nxt][1] = *(const half8*)(ph + 32 + koct);
                Bl[nxt][0] = *(const half8*)(pl + koct);
                Bl[nxt][1] = *(const half8*)(pl + 32 + koct);
            }
            #pragma unroll
            for (int rb = 0; rb < 4; ++rb) {
                floatx4 acc = {0.f, 0.f, 0.f, 0.f};
                acc = MFMA16(Ahi[rb][0], Bh[cur][0], acc);
                acc = MFMA16(Ahi[rb][1], Bh[cur][1], acc);
                acc = MFMA16(Ahi[rb][0], Bl[cur][0], acc);
                acc = MFMA16(Ahi[rb][1], Bl[cur][1], acc);
                acc = MFMA16(Alo[rb][0], Bh[cur][0], acc);
                acc = MFMA16(Alo[rb][1], Bh[cur][1], acc);
                #pragma unroll
                for (int r = 0; r < 4; ++r)
                    Dw[(rb*16 + crow + r)*17 + m16] = acc[r];
            }
            // lane = query row; scan this sub-tile's 16 candidates
            const float* drow = Dw + lane*17;
            int cglob = cand0 + st*16;           // local node id of candidate 0
            int selfc = qt*64 + lane - cglob;    // in [0,16) iff self in this tile
            if (pass == 0) {
                #pragma unroll
                for (int c = 0; c < 16; ++c) {
                    float s = fmaf(-2.f, drow[c], sqb[cglob + c]);
                    if (c == selfc) s = INFINITY;
                    float nb0 = fminf(bd[0], s);
                    #pragma unroll
                    for (int k = 15; k >= 1; --k) bd[k] = MED3(s, bd[k-1], bd[k]);
                    bd[0] = nb0;
                }
            } else {
                #pragma unroll
                for (int c = 0; c < 16; ++c) {
                    float s = fmaf(-2.f, drow[c], sqb[cglob + c]);
                    if (c == selfc) s = INFINITY;
                    if (s < tau) {
                        unsigned p = atomicAdd(&cntL[lane], 1u);
                        if (p < 16u) knn[gq*16 + p] = (unsigned short)(cglob + c);
                    } else if (s == tau) {
                        unsigned p = atomicAdd(&cntE[lane], 1u);
                        if (p < 16u) eqbuf[lane][p] = (unsigned short)(cglob + c);
                    }
                }
            }
        }
        if (pass == 0) {
            // merge 4 per-wave sorted value lists -> exact 16th-smallest tau per query
            __syncthreads();                 // all waves done with their D tiles
            float* md = &D[0][0];            // alias as md[64][65] (4160 <= 4352 floats)
            #pragma unroll
            for (int k = 0; k < 16; ++k) md[lane*65 + w*16 + k] = bd[k];
            __syncthreads();
            float b2[16];
            #pragma unroll
            for (int k = 0; k < 16; ++k) b2[k] = INFINITY;
            const float* mrow = md + lane*65;
            for (int c = 0; c < 64; ++c) {
                float s = mrow[c];
                float nb0 = fminf(b2[0], s);
                #pragma unroll
                for (int k = 15; k >= 1; --k) b2[k] = MED3(s, b2[k-1], b2[k]);
                b2[0] = nb0;
            }
            tau = b2[15];
            __syncthreads();                 // release md before pass-1 overwrites D
        }
    }
    __syncthreads();
    if (t < 64) {
        unsigned cL = cntL[t]; if (cL > 16u) cL = 16u;
        for (unsigned k = cL; k < 16u; ++k)
            knn[((size_t)g*M_ + qt*64 + t)*16 + k] = eqbuf[t][k - cL];
    }
}

// ---------------- EdgeConv: out_i = max_e ReLU(C_i + A_j)@W2 + b2 ----------------
#define RS 20   // padded row stride for hidT
__global__ __launch_bounds__(256) void edge_kernel(
    const float* __restrict__ h,     // [N,64] in (in-place out OK: only own row read)
    const float* __restrict__ A,     // [N,64]
    const unsigned short* __restrict__ knn, // [N,16] local idx
    const float* __restrict__ w1,    // [128,64]
    const float* __restrict__ b1,    // [64]
    const float* __restrict__ w2,    // [64,64]
    const float* __restrict__ b2,    // [64]
    float* __restrict__ hout)
{
    __shared__ float swd[64*64];   // W1a - W1b
    __shared__ float sw2[64*64];
    __shared__ float sb1[64], sb2[64];
    __shared__ float hS[4][64];
    __shared__ float hidT[4][64*RS];
    int t = threadIdx.x;
    for (int idx = t; idx < 4096; idx += 256) {
        swd[idx] = w1[idx] - w1[4096 + idx];
        sw2[idx] = w2[idx];
    }
    if (t < 64) { sb1[t] = b1[t]; sb2[t] = b2[t]; }
    __syncthreads();
    int lane = t & 63;
    int wid  = __builtin_amdgcn_readfirstlane(t >> 6);
    int base = blockIdx.x * 64 + wid * 16;
    int b    = blockIdx.x >> 4;        // 16 blocks per graph
    const float* Ab = A + (size_t)b*M_*H_;
    float* hsw = hS[wid];
    float* ht  = hidT[wid];
    for (int iter = 0; iter < 16; ++iter) {
        int i = base + iter;           // global node id
        hsw[lane] = h[(size_t)i*64 + lane];
        __syncthreads();
        float c = sb1[lane];
        #pragma unroll
        for (int g = 0; g < 64; ++g) c += hsw[g] * swd[g*64 + lane];
        const unsigned short* kn = knn + (size_t)i*16;
        #pragma unroll
        for (int e = 0; e < 16; ++e) {
            int j = kn[e];
            float v = c + Ab[(size_t)j*64 + lane];
            ht[lane*RS + e] = fmaxf(v, 0.f);
        }
        __syncthreads();
        float acc[16];
        #pragma unroll
        for (int e = 0; e < 16; ++e) acc[e] = 0.f;
        #pragma unroll 8
        for (int f = 0; f < 64; ++f) {
            float w = sw2[f*64 + lane];
            const float* hr = ht + f*RS;
            #pragma unroll
            for (int e = 0; e < 16; ++e) acc[e] += w * hr[e];
        }
        float m = acc[0];
        #pragma unroll
        for (int e = 1; e < 16; ++e) m = fmaxf(m, acc[e]);
        __syncthreads();
        hout[(size_t)i*64 + lane] = m + sb2[lane];
    }
}

// ---------------- mean-pool + output MLP ----------------
__global__ __launch_bounds__(256) void pool_kernel(
    const float* __restrict__ h,    // [N,64]
    const float* __restrict__ w1,   // [64,32]
    const float* __restrict__ b1,   // [32]
    const float* __restrict__ w2,   // [32,1]
    const float* __restrict__ b2,   // [1]
    float* __restrict__ out)        // [B]
{
    __shared__ float part[4][64];
    __shared__ float g[64];
    __shared__ float hid[32];
    int t = threadIdx.x;
    int o = t & 63, p = t >> 6;
    int b = blockIdx.x;
    const float* hb = h + (size_t)b*M_*H_;
    float s = 0.f;
    for (int m = p; m < M_; m += 4) s += hb[(size_t)m*64 + o];
    part[p][o] = s;
    __syncthreads();
    if (t < 64) g[t] = (part[0][t] + part[1][t] + part[2][t] + part[3][t]) * (1.f/M_);
    __syncthreads();
    if (t < 32) {
        float a = b1[t];
        for (int f = 0; f < 64; ++f) a += g[f] * w1[f*32 + t];
        hid[t] = fmaxf(a, 0.f);
    }
    __syncthreads();
    if (t == 0) {
        float a = b2[0];
        for (int f = 0; f < 32; ++f) a += hid[f] * w2[f];
        out[b] = a;
    }
}

extern "C" void kernel_launch(void* const* d_in, const int* in_sizes, int n_in,
                              void* d_out, int out_size, void* d_ws, size_t ws_size,
                              hipStream_t stream)
{
    (void)in_sizes; (void)n_in; (void)out_size; (void)ws_size;
    const float* x      = (const float*)d_in[0];
    const float* enc_w1 = (const float*)d_in[2];
    const float* enc_b1 = (const float*)d_in[3];
    const float* enc_w2 = (const float*)d_in[4];
    const float* enc_b2 = (const float*)d_in[5];
    const float* ec1_w1 = (const float*)d_in[6];
    const float* ec1_b1 = (const float*)d_in[7];
    const float* ec1_w2 = (const float*)d_in[8];
    const float* ec1_b2 = (const float*)d_in[9];
    const float* ec2_w1 = (const float*)d_in[10];
    const float* ec2_b1 = (const float*)d_in[11];
    const float* ec2_w2 = (const float*)d_in[12];
    const float* ec2_b2 = (const float*)d_in[13];
    const float* out_w1 = (const float*)d_in[14];
    const float* out_b1 = (const float*)d_in[15];
    const float* out_w2 = (const float*)d_in[16];
    const float* out_b2 = (const float*)d_in[17];

    // ws layout, 34.25 MB total. Region2 (16 MB) time-shared:
    //   (hhi|hlo) live producer->knn;  A lives gemmA->edge.  Never overlap.
    char* ws = (char*)d_ws;
    float*          h   = (float*)(ws);                                  // 16 MB
    char*           r2  = ws + (size_t)N_*64*4;                          // 16 MB
    _Float16*       hhi = (_Float16*)r2;                                 //  8 MB
    _Float16*       hlo = (_Float16*)(r2 + (size_t)N_*64*2);             //  8 MB
    float*          A   = (float*)r2;                                    // 16 MB (alias)
    unsigned short* idx = (unsigned short*)(ws + (size_t)N_*64*4*2);     //  2 MB
    float*          sq  = (float*)(ws + (size_t)N_*64*4*2 + (size_t)N_*16*2); // 256 KB

    enc_kernel<<<N_/256, 256, 0, stream>>>(x, enc_w1, enc_b1, enc_w2, enc_b2,
                                           h, hhi, hlo, sq);
    // layer 1
    knn_kernel <<<B_*16, 256, 0, stream>>>(hhi, hlo, sq, idx);
    gemmA_kernel<<<N_/256, 256, 0, stream>>>(h, ec1_w1, A);   // clobbers hhi/hlo (dead)
    edge_kernel<<<N_/64, 256, 0, stream>>>(h, A, idx, ec1_w1, ec1_b1, ec1_w2, ec1_b2, h);
    // layer 2
    convert_kernel<<<N_/64, 256, 0, stream>>>(h, hhi, hlo, sq); // clobbers A (dead)
    knn_kernel <<<B_*16, 256, 0, stream>>>(hhi, hlo, sq, idx);
    gemmA_kernel<<<N_/256, 256, 0, stream>>>(h, ec2_w1, A);
    edge_kernel<<<N_/64, 256, 0, stream>>>(h, A, idx, ec2_w1, ec2_b1, ec2_w2, ec2_b2, h);
    // pool + output MLP
    pool_kernel<<<B_, 256, 0, stream>>>(h, out_w1, out_b1, out_w2, out_b2, (float*)d_out);
}

// Round 7
// 907.479 us; speedup vs baseline: 6.3357x; 6.3357x over previous
//
#include <hip/hip_runtime.h>
#include <math.h>

#define B_ 64
#define M_ 1024
#define H_ 64
#define N_ (B_*M_)   // 65536

typedef _Float16 half8 __attribute__((ext_vector_type(8)));
typedef float  floatx4 __attribute__((ext_vector_type(4)));

#define MFMA16(a,b,c) __builtin_amdgcn_mfma_f32_16x16x32_f16(a,b,c,0,0,0)
#define MED3(a,b,c)   __builtin_amdgcn_fmed3f(a,b,c)

// ---------------- encoder: h = relu(relu(x@w1+b1)@w2+b2) (+ f16 split + sq) ------
__global__ __launch_bounds__(256) void enc_kernel(
    const float* __restrict__ x,     // [N,4]
    const float* __restrict__ w1,    // [4,32]
    const float* __restrict__ b1,    // [32]
    const float* __restrict__ w2,    // [32,64]
    const float* __restrict__ b2,    // [64]
    float* __restrict__ h,           // [N,64]
    _Float16* __restrict__ hhi,      // [N,64]
    _Float16* __restrict__ hlo,      // [N,64]
    float* __restrict__ sq)          // [N]
{
    __shared__ float sw1[4*32];
    __shared__ float sb1[32];
    __shared__ float sw2[32*64];
    __shared__ float sb2[64];
    int t = threadIdx.x;
    for (int i = t; i < 128; i += 256) sw1[i] = w1[i];
    if (t < 32) sb1[t] = b1[t];
    for (int i = t; i < 2048; i += 256) sw2[i] = w2[i];
    if (t < 64) sb2[t] = b2[t];
    __syncthreads();
    int n = blockIdx.x * 256 + t;
    float4 xv = *(const float4*)(x + (size_t)n*4);
    float hid[32];
    #pragma unroll
    for (int o = 0; o < 32; ++o) {
        float a = sb1[o] + xv.x*sw1[0*32+o] + xv.y*sw1[1*32+o]
                        + xv.z*sw1[2*32+o] + xv.w*sw1[3*32+o];
        hid[o] = fmaxf(a, 0.f);
    }
    float* hout = h + (size_t)n*64;
    float sqa = 0.f;
    #pragma unroll 4
    for (int oc = 0; oc < 16; ++oc) {
        float4 acc = make_float4(sb2[oc*4+0], sb2[oc*4+1], sb2[oc*4+2], sb2[oc*4+3]);
        #pragma unroll
        for (int f = 0; f < 32; ++f) {
            float4 w = *(const float4*)(sw2 + f*64 + oc*4);
            float hv = hid[f];
            acc.x += hv*w.x; acc.y += hv*w.y; acc.z += hv*w.z; acc.w += hv*w.w;
        }
        acc.x = fmaxf(acc.x,0.f); acc.y = fmaxf(acc.y,0.f);
        acc.z = fmaxf(acc.z,0.f); acc.w = fmaxf(acc.w,0.f);
        *(float4*)(hout + oc*4) = acc;
        sqa += acc.x*acc.x + acc.y*acc.y + acc.z*acc.z + acc.w*acc.w;
        union { _Float16 f[4]; uint2 u; } Hh, Hl;
        Hh.f[0]=(_Float16)acc.x; Hh.f[1]=(_Float16)acc.y;
        Hh.f[2]=(_Float16)acc.z; Hh.f[3]=(_Float16)acc.w;
        Hl.f[0]=(_Float16)(acc.x-(float)Hh.f[0]); Hl.f[1]=(_Float16)(acc.y-(float)Hh.f[1]);
        Hl.f[2]=(_Float16)(acc.z-(float)Hh.f[2]); Hl.f[3]=(_Float16)(acc.w-(float)Hh.f[3]);
        *(uint2*)(hhi + (size_t)n*64 + oc*4) = Hh.u;
        *(uint2*)(hlo + (size_t)n*64 + oc*4) = Hl.u;
    }
    sq[n] = sqa;
}

// ---------------- convert: h -> (hhi, hlo, sq)  (after edge layer 1) -------------
__global__ __launch_bounds__(256) void convert_kernel(
    const float* __restrict__ h,
    _Float16* __restrict__ hhi, _Float16* __restrict__ hlo,
    float* __restrict__ sq)
{
    int t = threadIdx.x, lane = t & 63, w = t >> 6;
    int base = blockIdx.x * 64 + w * 16;
    for (int it = 0; it < 16; ++it) {
        int i = base + it;
        float v = h[(size_t)i*64 + lane];
        _Float16 hi = (_Float16)v;
        _Float16 lo = (_Float16)(v - (float)hi);
        hhi[(size_t)i*64 + lane] = hi;
        hlo[(size_t)i*64 + lane] = lo;
        float s = v*v;
        #pragma unroll
        for (int off = 1; off < 64; off <<= 1) s += __shfl_xor(s, off, 64);
        if (lane == 0) sq[i] = s;
    }
}

// ---------------- A = h @ W1b  (W1b = rows 64..127 of w1) ----------------
__global__ __launch_bounds__(256) void gemmA_kernel(
    const float* __restrict__ h,
    const float* __restrict__ w1,   // [128,64]
    float* __restrict__ A)
{
    __shared__ float sw[64*64];
    int t = threadIdx.x;
    for (int idx = t; idx < 4096; idx += 256) sw[idx] = w1[4096 + idx];
    __syncthreads();
    int n = blockIdx.x * 256 + t;
    float4 hv[16];
    const float* src = h + (size_t)n*64;
    #pragma unroll
    for (int c = 0; c < 16; ++c) hv[c] = *(const float4*)(src + c*4);
    float* dst = A + (size_t)n*64;
    #pragma unroll 2
    for (int oc = 0; oc < 16; ++oc) {
        float4 acc = make_float4(0.f,0.f,0.f,0.f);
        #pragma unroll
        for (int f = 0; f < 64; ++f) {
            float xv = ((const float*)hv)[f];
            float4 w = *(const float4*)(sw + f*64 + oc*4);
            acc.x += xv*w.x; acc.y += xv*w.y; acc.z += xv*w.z; acc.w += xv*w.w;
        }
        *(float4*)(dst + oc*4) = acc;
    }
}

// ---------------- kNN v6: R4 skeleton, 32-cand chunks (unrolled, static regs),
//                  sq staged in LDS, XCD swizzle, NO occupancy cap --------------
// block = 64 queries x 1024 candidates; 4 waves split candidates (256 each).
// Rank score s = sq_j - 2*dot(h_i,h_j); dot via f16 split (hi*hi+hi*lo+lo*hi).
// Pass 0: med3-network top-16 values -> exact tau. Pass 1: recompute (bit-identical)
// and collect indices with s < tau, tie-fill s == tau.
__global__ __launch_bounds__(256) void knn_kernel(
    const _Float16* __restrict__ hhi,
    const _Float16* __restrict__ hlo,
    const float* __restrict__ sqg,
    unsigned short* __restrict__ knn)    // [N,16]
{
    __shared__ float D[4][64*33];         // per-wave 64q x 32c tile, stride 33 (33.8 KB)
    __shared__ float sqS[1024];           // staged sq for the whole graph's 1024 nodes
    __shared__ unsigned int cntL[64], cntE[64];
    __shared__ unsigned short eqbuf[64][16];
    int t = threadIdx.x, lane = t & 63, w = t >> 6;
    int bi = blockIdx.x;
    int g  = (bi & 7) | ((bi >> 7) << 3);  // 16 blocks/graph share bi%8 -> same XCD L2
    int qt = (bi >> 3) & 15;
    const _Float16* hhig = hhi + (size_t)g*M_*64;
    const _Float16* hlog = hlo + (size_t)g*M_*64;
    const float*    sqb  = sqg + (size_t)g*M_;
    if (t < 64) { cntL[t] = 0; cntE[t] = 0; }
    ((float4*)sqS)[t] = ((const float4*)sqb)[t];   // 256 threads x 16B = 4 KB

    // A fragments (queries): lane holds A[m=lane&15][k=(lane>>4)*8 + j]
    int m16  = lane & 15;
    int koct = (lane >> 4) * 8;
    half8 Ahi[4][2], Alo[4][2];
    #pragma unroll
    for (int rb = 0; rb < 4; ++rb) {
        const _Float16* ph = hhig + (size_t)(qt*64 + rb*16 + m16)*64;
        const _Float16* pl = hlog + (size_t)(qt*64 + rb*16 + m16)*64;
        Ahi[rb][0] = *(const half8*)(ph + koct);
        Ahi[rb][1] = *(const half8*)(ph + 32 + koct);
        Alo[rb][0] = *(const half8*)(pl + koct);
        Alo[rb][1] = *(const half8*)(pl + 32 + koct);
    }
    float* Dw   = D[w];
    int    crow = (lane >> 4) * 4;   // C/D: col=lane&15, row=(lane>>4)*4+reg
    float  bd[16];
    #pragma unroll
    for (int k = 0; k < 16; ++k) bd[k] = INFINITY;
    float tau = 0.f;
    size_t gq = (size_t)g*M_ + qt*64 + lane;
    int cand0 = w*256;               // this wave's candidate range base
    __syncthreads();                 // sqS ready

    for (int pass = 0; pass < 2; ++pass) {
        #pragma unroll
        for (int cc = 0; cc < 8; ++cc) {      // 8 chunks of 32 candidates (static!)
            int cbase = cand0 + cc*32;
            half8 Bhi[2][2], Blo[2][2];
            #pragma unroll
            for (int cb = 0; cb < 2; ++cb) {
                const _Float16* ph = hhig + (size_t)(cbase + cb*16 + m16)*64;
                const _Float16* pl = hlog + (size_t)(cbase + cb*16 + m16)*64;
                Bhi[cb][0] = *(const half8*)(ph + koct);
                Bhi[cb][1] = *(const half8*)(ph + 32 + koct);
                Blo[cb][0] = *(const half8*)(pl + koct);
                Blo[cb][1] = *(const half8*)(pl + 32 + koct);
            }
            #pragma unroll
            for (int rb = 0; rb < 4; ++rb) {
                #pragma unroll
                for (int cb = 0; cb < 2; ++cb) {
                    floatx4 acc = {0.f, 0.f, 0.f, 0.f};
                    acc = MFMA16(Ahi[rb][0], Bhi[cb][0], acc);
                    acc = MFMA16(Ahi[rb][1], Bhi[cb][1], acc);
                    acc = MFMA16(Ahi[rb][0], Blo[cb][0], acc);
                    acc = MFMA16(Ahi[rb][1], Blo[cb][1], acc);
                    acc = MFMA16(Alo[rb][0], Bhi[cb][0], acc);
                    acc = MFMA16(Alo[rb][1], Bhi[cb][1], acc);
                    #pragma unroll
                    for (int r = 0; r < 4; ++r)
                        Dw[(rb*16 + crow + r)*33 + cb*16 + m16] = acc[r];
                }
            }
            // lane = query row; scan this chunk's 32 candidates
            const float* drow = Dw + lane*33;
            int selfc = qt*64 + lane - cbase;    // in [0,32) iff self in this chunk
            if (pass == 0) {
                #pragma unroll
                for (int c = 0; c < 32; ++c) {
                    float s = fmaf(-2.f, drow[c], sqS[cbase + c]);
                    if (c == selfc) s = INFINITY;
                    float nb0 = fminf(bd[0], s);
                    #pragma unroll
                    for (int k = 15; k >= 1; --k) bd[k] = MED3(s, bd[k-1], bd[k]);
                    bd[0] = nb0;
                }
            } else {
                #pragma unroll
                for (int c = 0; c < 32; ++c) {
                    float s = fmaf(-2.f, drow[c], sqS[cbase + c]);
                    if (c == selfc) s = INFINITY;
                    if (s < tau) {
                        unsigned p = atomicAdd(&cntL[lane], 1u);
                        if (p < 16u) knn[gq*16 + p] = (unsigned short)(cbase + c);
                    } else if (s == tau) {
                        unsigned p = atomicAdd(&cntE[lane], 1u);
                        if (p < 16u) eqbuf[lane][p] = (unsigned short)(cbase + c);
                    }
                }
            }
        }
        if (pass == 0) {
            // merge 4 per-wave sorted value lists -> exact 16th-smallest tau per query
            __syncthreads();                 // all waves done with their D tiles
            float* md = &D[0][0];            // alias as md[64][65]: 4160 <= 2*2112 floats
            #pragma unroll
            for (int k = 0; k < 16; ++k) md[lane*65 + w*16 + k] = bd[k];
            __syncthreads();
            float b2[16];
            #pragma unroll
            for (int k = 0; k < 16; ++k) b2[k] = INFINITY;
            const float* mrow = md + lane*65;
            for (int c = 0; c < 64; ++c) {
                float s = mrow[c];
                float nb0 = fminf(b2[0], s);
                #pragma unroll
                for (int k = 15; k >= 1; --k) b2[k] = MED3(s, b2[k-1], b2[k]);
                b2[0] = nb0;
            }
            tau = b2[15];
            __syncthreads();                 // release md before pass-1 overwrites D
        }
    }
    __syncthreads();
    if (t < 64) {
        unsigned cL = cntL[t]; if (cL > 16u) cL = 16u;
        for (unsigned k = cL; k < 16u; ++k)
            knn[((size_t)g*M_ + qt*64 + t)*16 + k] = eqbuf[t][k - cL];
    }
}

// ---------------- EdgeConv: out_i = max_e ReLU(C_i + A_j)@W2 + b2 ----------------
#define RS 20   // padded row stride for hidT
__global__ __launch_bounds__(256) void edge_kernel(
    const float* __restrict__ h,     // [N,64] in (in-place out OK: only own row read)
    const float* __restrict__ A,     // [N,64]
    const unsigned short* __restrict__ knn, // [N,16] local idx
    const float* __restrict__ w1,    // [128,64]
    const float* __restrict__ b1,    // [64]
    const float* __restrict__ w2,    // [64,64]
    const float* __restrict__ b2,    // [64]
    float* __restrict__ hout)
{
    __shared__ float swd[64*64];   // W1a - W1b
    __shared__ float sw2[64*64];
    __shared__ float sb1[64], sb2[64];
    __shared__ float hS[4][64];
    __shared__ float hidT[4][64*RS];
    int t = threadIdx.x;
    for (int idx = t; idx < 4096; idx += 256) {
        swd[idx] = w1[idx] - w1[4096 + idx];
        sw2[idx] = w2[idx];
    }
    if (t < 64) { sb1[t] = b1[t]; sb2[t] = b2[t]; }
    __syncthreads();
    int lane = t & 63;
    int wid  = __builtin_amdgcn_readfirstlane(t >> 6);
    int base = blockIdx.x * 64 + wid * 16;
    int b    = blockIdx.x >> 4;        // 16 blocks per graph
    const float* Ab = A + (size_t)b*M_*H_;
    float* hsw = hS[wid];
    float* ht  = hidT[wid];
    for (int iter = 0; iter < 16; ++iter) {
        int i = base + iter;           // global node id
        hsw[lane] = h[(size_t)i*64 + lane];
        __syncthreads();
        float c = sb1[lane];
        #pragma unroll
        for (int g = 0; g < 64; ++g) c += hsw[g] * swd[g*64 + lane];
        const unsigned short* kn = knn + (size_t)i*16;
        #pragma unroll
        for (int e = 0; e < 16; ++e) {
            int j = kn[e];
            float v = c + Ab[(size_t)j*64 + lane];
            ht[lane*RS + e] = fmaxf(v, 0.f);
        }
        __syncthreads();
        float acc[16];
        #pragma unroll
        for (int e = 0; e < 16; ++e) acc[e] = 0.f;
        #pragma unroll 8
        for (int f = 0; f < 64; ++f) {
            float w = sw2[f*64 + lane];
            const float* hr = ht + f*RS;
            #pragma unroll
            for (int e = 0; e < 16; ++e) acc[e] += w * hr[e];
        }
        float m = acc[0];
        #pragma unroll
        for (int e = 1; e < 16; ++e) m = fmaxf(m, acc[e]);
        __syncthreads();
        hout[(size_t)i*64 + lane] = m + sb2[lane];
    }
}

// ---------------- mean-pool + output MLP ----------------
__global__ __launch_bounds__(256) void pool_kernel(
    const float* __restrict__ h,    // [N,64]
    const float* __restrict__ w1,   // [64,32]
    const float* __restrict__ b1,   // [32]
    const float* __restrict__ w2,   // [32,1]
    const float* __restrict__ b2,   // [1]
    float* __restrict__ out)        // [B]
{
    __shared__ float part[4][64];
    __shared__ float g[64];
    __shared__ float hid[32];
    int t = threadIdx.x;
    int o = t & 63, p = t >> 6;
    int b = blockIdx.x;
    const float* hb = h + (size_t)b*M_*H_;
    float s = 0.f;
    for (int m = p; m < M_; m += 4) s += hb[(size_t)m*64 + o];
    part[p][o] = s;
    __syncthreads();
    if (t < 64) g[t] = (part[0][t] + part[1][t] + part[2][t] + part[3][t]) * (1.f/M_);
    __syncthreads();
    if (t < 32) {
        float a = b1[t];
        for (int f = 0; f < 64; ++f) a += g[f] * w1[f*32 + t];
        hid[t] = fmaxf(a, 0.f);
    }
    __syncthreads();
    if (t == 0) {
        float a = b2[0];
        for (int f = 0; f < 32; ++f) a += hid[f] * w2[f];
        out[b] = a;
    }
}

extern "C" void kernel_launch(void* const* d_in, const int* in_sizes, int n_in,
                              void* d_out, int out_size, void* d_ws, size_t ws_size,
                              hipStream_t stream)
{
    (void)in_sizes; (void)n_in; (void)out_size; (void)ws_size;
    const float* x      = (const float*)d_in[0];
    const float* enc_w1 = (const float*)d_in[2];
    const float* enc_b1 = (const float*)d_in[3];
    const float* enc_w2 = (const float*)d_in[4];
    const float* enc_b2 = (const float*)d_in[5];
    const float* ec1_w1 = (const float*)d_in[6];
    const float* ec1_b1 = (const float*)d_in[7];
    const float* ec1_w2 = (const float*)d_in[8];
    const float* ec1_b2 = (const float*)d_in[9];
    const float* ec2_w1 = (const float*)d_in[10];
    const float* ec2_b1 = (const float*)d_in[11];
    const float* ec2_w2 = (const float*)d_in[12];
    const float* ec2_b2 = (const float*)d_in[13];
    const float* out_w1 = (const float*)d_in[14];
    const float* out_b1 = (const float*)d_in[15];
    const float* out_w2 = (const float*)d_in[16];
    const float* out_b2 = (const float*)d_in[17];

    // ws layout, 34.25 MB total. Region2 (16 MB) time-shared:
    //   (hhi|hlo) live producer->knn;  A lives gemmA->edge.  Never overlap.
    char* ws = (char*)d_ws;
    float*          h   = (float*)(ws);                                  // 16 MB
    char*           r2  = ws + (size_t)N_*64*4;                          // 16 MB
    _Float16*       hhi = (_Float16*)r2;                                 //  8 MB
    _Float16*       hlo = (_Float16*)(r2 + (size_t)N_*64*2);             //  8 MB
    float*          A   = (float*)r2;                                    // 16 MB (alias)
    unsigned short* idx = (unsigned short*)(ws + (size_t)N_*64*4*2);     //  2 MB
    float*          sq  = (float*)(ws + (size_t)N_*64*4*2 + (size_t)N_*16*2); // 256 KB

    enc_kernel<<<N_/256, 256, 0, stream>>>(x, enc_w1, enc_b1, enc_w2, enc_b2,
                                           h, hhi, hlo, sq);
    // layer 1
    knn_kernel <<<B_*16, 256, 0, stream>>>(hhi, hlo, sq, idx);
    gemmA_kernel<<<N_/256, 256, 0, stream>>>(h, ec1_w1, A);   // clobbers hhi/hlo (dead)
    edge_kernel<<<N_/64, 256, 0, stream>>>(h, A, idx, ec1_w1, ec1_b1, ec1_w2, ec1_b2, h);
    // layer 2
    convert_kernel<<<N_/64, 256, 0, stream>>>(h, hhi, hlo, sq); // clobbers A (dead)
    knn_kernel <<<B_*16, 256, 0, stream>>>(hhi, hlo, sq, idx);
    gemmA_kernel<<<N_/256, 256, 0, stream>>>(h, ec2_w1, A);
    edge_kernel<<<N_/64, 256, 0, stream>>>(h, A, idx, ec2_w1, ec2_b1, ec2_w2, ec2_b2, h);
    // pool + output MLP
    pool_kernel<<<B_, 256, 0, stream>>>(h, out_w1, out_b1, out_w2, out_b2, (float*)d_out);
}

// Round 8
// 602.434 us; speedup vs baseline: 9.5438x; 1.5064x over previous
//
#include <hip/hip_runtime.h>
#include <math.h>

#define B_ 64
#define M_ 1024
#define H_ 64
#define N_ (B_*M_)   // 65536

typedef _Float16 half8 __attribute__((ext_vector_type(8)));
typedef float  floatx4 __attribute__((ext_vector_type(4)));

#define MFMA16(a,b,c) __builtin_amdgcn_mfma_f32_16x16x32_f16(a,b,c,0,0,0)
#define MED3(a,b,c)   __builtin_amdgcn_fmed3f(a,b,c)

// ---------------- encoder: h = relu(relu(x@w1+b1)@w2+b2) (+ f16 split + sq) ------
__global__ __launch_bounds__(256) void enc_kernel(
    const float* __restrict__ x,     // [N,4]
    const float* __restrict__ w1,    // [4,32]
    const float* __restrict__ b1,    // [32]
    const float* __restrict__ w2,    // [32,64]
    const float* __restrict__ b2,    // [64]
    float* __restrict__ h,           // [N,64]
    _Float16* __restrict__ hhi,      // [N,64]
    _Float16* __restrict__ hlo,      // [N,64]
    float* __restrict__ sq)          // [N]
{
    __shared__ float sw1[4*32];
    __shared__ float sb1[32];
    __shared__ float sw2[32*64];
    __shared__ float sb2[64];
    int t = threadIdx.x;
    for (int i = t; i < 128; i += 256) sw1[i] = w1[i];
    if (t < 32) sb1[t] = b1[t];
    for (int i = t; i < 2048; i += 256) sw2[i] = w2[i];
    if (t < 64) sb2[t] = b2[t];
    __syncthreads();
    int n = blockIdx.x * 256 + t;
    float4 xv = *(const float4*)(x + (size_t)n*4);
    float hid[32];
    #pragma unroll
    for (int o = 0; o < 32; ++o) {
        float a = sb1[o] + xv.x*sw1[0*32+o] + xv.y*sw1[1*32+o]
                        + xv.z*sw1[2*32+o] + xv.w*sw1[3*32+o];
        hid[o] = fmaxf(a, 0.f);
    }
    float* hout = h + (size_t)n*64;
    float sqa = 0.f;
    #pragma unroll 4
    for (int oc = 0; oc < 16; ++oc) {
        float4 acc = make_float4(sb2[oc*4+0], sb2[oc*4+1], sb2[oc*4+2], sb2[oc*4+3]);
        #pragma unroll
        for (int f = 0; f < 32; ++f) {
            float4 w = *(const float4*)(sw2 + f*64 + oc*4);
            float hv = hid[f];
            acc.x += hv*w.x; acc.y += hv*w.y; acc.z += hv*w.z; acc.w += hv*w.w;
        }
        acc.x = fmaxf(acc.x,0.f); acc.y = fmaxf(acc.y,0.f);
        acc.z = fmaxf(acc.z,0.f); acc.w = fmaxf(acc.w,0.f);
        *(float4*)(hout + oc*4) = acc;
        sqa += acc.x*acc.x + acc.y*acc.y + acc.z*acc.z + acc.w*acc.w;
        union { _Float16 f[4]; uint2 u; } Hh, Hl;
        Hh.f[0]=(_Float16)acc.x; Hh.f[1]=(_Float16)acc.y;
        Hh.f[2]=(_Float16)acc.z; Hh.f[3]=(_Float16)acc.w;
        Hl.f[0]=(_Float16)(acc.x-(float)Hh.f[0]); Hl.f[1]=(_Float16)(acc.y-(float)Hh.f[1]);
        Hl.f[2]=(_Float16)(acc.z-(float)Hh.f[2]); Hl.f[3]=(_Float16)(acc.w-(float)Hh.f[3]);
        *(uint2*)(hhi + (size_t)n*64 + oc*4) = Hh.u;
        *(uint2*)(hlo + (size_t)n*64 + oc*4) = Hl.u;
    }
    sq[n] = sqa;
}

// ---------------- convert: h -> (hhi, hlo, sq)  (after edge layer 1) -------------
__global__ __launch_bounds__(256) void convert_kernel(
    const float* __restrict__ h,
    _Float16* __restrict__ hhi, _Float16* __restrict__ hlo,
    float* __restrict__ sq)
{
    int t = threadIdx.x, lane = t & 63, w = t >> 6;
    int base = blockIdx.x * 64 + w * 16;
    for (int it = 0; it < 16; ++it) {
        int i = base + it;
        float v = h[(size_t)i*64 + lane];
        _Float16 hi = (_Float16)v;
        _Float16 lo = (_Float16)(v - (float)hi);
        hhi[(size_t)i*64 + lane] = hi;
        hlo[(size_t)i*64 + lane] = lo;
        float s = v*v;
        #pragma unroll
        for (int off = 1; off < 64; off <<= 1) s += __shfl_xor(s, off, 64);
        if (lane == 0) sq[i] = s;
    }
}

// ---------------- A = h @ W1b  (W1b = rows 64..127 of w1) ----------------
__global__ __launch_bounds__(256) void gemmA_kernel(
    const float* __restrict__ h,
    const float* __restrict__ w1,   // [128,64]
    float* __restrict__ A)
{
    __shared__ float sw[64*64];
    int t = threadIdx.x;
    for (int idx = t; idx < 4096; idx += 256) sw[idx] = w1[4096 + idx];
    __syncthreads();
    int n = blockIdx.x * 256 + t;
    float4 hv[16];
    const float* src = h + (size_t)n*64;
    #pragma unroll
    for (int c = 0; c < 16; ++c) hv[c] = *(const float4*)(src + c*4);
    float* dst = A + (size_t)n*64;
    #pragma unroll 2
    for (int oc = 0; oc < 16; ++oc) {
        float4 acc = make_float4(0.f,0.f,0.f,0.f);
        #pragma unroll
        for (int f = 0; f < 64; ++f) {
            float xv = ((const float*)hv)[f];
            float4 w = *(const float4*)(sw + f*64 + oc*4);
            acc.x += xv*w.x; acc.y += xv*w.y; acc.z += xv*w.z; acc.w += xv*w.w;
        }
        *(float4*)(dst + oc*4) = acc;
    }
}

// ---------------- kNN v6 (unchanged from R7, proven) ----------------
__global__ __launch_bounds__(256) void knn_kernel(
    const _Float16* __restrict__ hhi,
    const _Float16* __restrict__ hlo,
    const float* __restrict__ sqg,
    unsigned short* __restrict__ knn)    // [N,16]
{
    __shared__ float D[4][64*33];         // per-wave 64q x 32c tile, stride 33 (33.8 KB)
    __shared__ float sqS[1024];           // staged sq for the whole graph's 1024 nodes
    __shared__ unsigned int cntL[64], cntE[64];
    __shared__ unsigned short eqbuf[64][16];
    int t = threadIdx.x, lane = t & 63, w = t >> 6;
    int bi = blockIdx.x;
    int g  = (bi & 7) | ((bi >> 7) << 3);  // 16 blocks/graph share bi%8 -> same XCD L2
    int qt = (bi >> 3) & 15;
    const _Float16* hhig = hhi + (size_t)g*M_*64;
    const _Float16* hlog = hlo + (size_t)g*M_*64;
    const float*    sqb  = sqg + (size_t)g*M_;
    if (t < 64) { cntL[t] = 0; cntE[t] = 0; }
    ((float4*)sqS)[t] = ((const float4*)sqb)[t];   // 256 threads x 16B = 4 KB

    int m16  = lane & 15;
    int koct = (lane >> 4) * 8;
    half8 Ahi[4][2], Alo[4][2];
    #pragma unroll
    for (int rb = 0; rb < 4; ++rb) {
        const _Float16* ph = hhig + (size_t)(qt*64 + rb*16 + m16)*64;
        const _Float16* pl = hlog + (size_t)(qt*64 + rb*16 + m16)*64;
        Ahi[rb][0] = *(const half8*)(ph + koct);
        Ahi[rb][1] = *(const half8*)(ph + 32 + koct);
        Alo[rb][0] = *(const half8*)(pl + koct);
        Alo[rb][1] = *(const half8*)(pl + 32 + koct);
    }
    float* Dw   = D[w];
    int    crow = (lane >> 4) * 4;   // C/D: col=lane&15, row=(lane>>4)*4+reg
    float  bd[16];
    #pragma unroll
    for (int k = 0; k < 16; ++k) bd[k] = INFINITY;
    float tau = 0.f;
    size_t gq = (size_t)g*M_ + qt*64 + lane;
    int cand0 = w*256;               // this wave's candidate range base
    __syncthreads();                 // sqS ready

    for (int pass = 0; pass < 2; ++pass) {
        #pragma unroll
        for (int cc = 0; cc < 8; ++cc) {      // 8 chunks of 32 candidates (static!)
            int cbase = cand0 + cc*32;
            half8 Bhi[2][2], Blo[2][2];
            #pragma unroll
            for (int cb = 0; cb < 2; ++cb) {
                const _Float16* ph = hhig + (size_t)(cbase + cb*16 + m16)*64;
                const _Float16* pl = hlog + (size_t)(cbase + cb*16 + m16)*64;
                Bhi[cb][0] = *(const half8*)(ph + koct);
                Bhi[cb][1] = *(const half8*)(ph + 32 + koct);
                Blo[cb][0] = *(const half8*)(pl + koct);
                Blo[cb][1] = *(const half8*)(pl + 32 + koct);
            }
            #pragma unroll
            for (int rb = 0; rb < 4; ++rb) {
                #pragma unroll
                for (int cb = 0; cb < 2; ++cb) {
                    floatx4 acc = {0.f, 0.f, 0.f, 0.f};
                    acc = MFMA16(Ahi[rb][0], Bhi[cb][0], acc);
                    acc = MFMA16(Ahi[rb][1], Bhi[cb][1], acc);
                    acc = MFMA16(Ahi[rb][0], Blo[cb][0], acc);
                    acc = MFMA16(Ahi[rb][1], Blo[cb][1], acc);
                    acc = MFMA16(Alo[rb][0], Bhi[cb][0], acc);
                    acc = MFMA16(Alo[rb][1], Bhi[cb][1], acc);
                    #pragma unroll
                    for (int r = 0; r < 4; ++r)
                        Dw[(rb*16 + crow + r)*33 + cb*16 + m16] = acc[r];
                }
            }
            const float* drow = Dw + lane*33;
            int selfc = qt*64 + lane - cbase;    // in [0,32) iff self in this chunk
            if (pass == 0) {
                #pragma unroll
                for (int c = 0; c < 32; ++c) {
                    float s = fmaf(-2.f, drow[c], sqS[cbase + c]);
                    if (c == selfc) s = INFINITY;
                    float nb0 = fminf(bd[0], s);
                    #pragma unroll
                    for (int k = 15; k >= 1; --k) bd[k] = MED3(s, bd[k-1], bd[k]);
                    bd[0] = nb0;
                }
            } else {
                #pragma unroll
                for (int c = 0; c < 32; ++c) {
                    float s = fmaf(-2.f, drow[c], sqS[cbase + c]);
                    if (c == selfc) s = INFINITY;
                    if (s < tau) {
                        unsigned p = atomicAdd(&cntL[lane], 1u);
                        if (p < 16u) knn[gq*16 + p] = (unsigned short)(cbase + c);
                    } else if (s == tau) {
                        unsigned p = atomicAdd(&cntE[lane], 1u);
                        if (p < 16u) eqbuf[lane][p] = (unsigned short)(cbase + c);
                    }
                }
            }
        }
        if (pass == 0) {
            __syncthreads();                 // all waves done with their D tiles
            float* md = &D[0][0];            // alias as md[64][65]
            #pragma unroll
            for (int k = 0; k < 16; ++k) md[lane*65 + w*16 + k] = bd[k];
            __syncthreads();
            float b2[16];
            #pragma unroll
            for (int k = 0; k < 16; ++k) b2[k] = INFINITY;
            const float* mrow = md + lane*65;
            for (int c = 0; c < 64; ++c) {
                float s = mrow[c];
                float nb0 = fminf(b2[0], s);
                #pragma unroll
                for (int k = 15; k >= 1; --k) b2[k] = MED3(s, b2[k-1], b2[k]);
                b2[0] = nb0;
            }
            tau = b2[15];
            __syncthreads();                 // release md before pass-1 overwrites D
        }
    }
    __syncthreads();
    if (t < 64) {
        unsigned cL = cntL[t]; if (cL > 16u) cL = 16u;
        for (unsigned k = cL; k < 16u; ++k)
            knn[((size_t)g*M_ + qt*64 + t)*16 + k] = eqbuf[t][k - cL];
    }
}

// ---------------- EdgeConv v2 (MFMA): out_i = max_e ReLU(C_i + A_j)@W2 + b2 ------
// Wave handles 16 nodes. Phase 1: C[16x64] = h@(W1a-W1b)+b1 via f16-split MFMA,
// staged to LDS. Phase 2 per node: gather A_j rows, msg=relu(C+A_j) -> f16-split
// A-frags, msg@W2 via MFMA (W2 B-frags in VGPRs), max over edge rows via shfl.
__global__ __launch_bounds__(256) void edge_kernel(
    const float* __restrict__ h,     // [N,64] (in-place out OK: own rows read first)
    const float* __restrict__ A,     // [N,64]
    const unsigned short* __restrict__ knn, // [N,16] local idx
    const float* __restrict__ w1,    // [128,64]
    const float* __restrict__ b1,    // [64]
    const float* __restrict__ w2,    // [64,64]
    const float* __restrict__ b2,    // [64]
    float* __restrict__ hout)
{
    __shared__ _Float16 wdf[16*64*8];   // Wd B-frags pre-swizzled (16 KB)
    __shared__ _Float16 w2f[16*64*8];   // W2 B-frags pre-swizzled (16 KB)
    __shared__ float Cs[4][16][68];     // per-wave C tile (17.4 KB)
    int t = threadIdx.x;
    // pre-swizzle both weight matrices into B-frag layout (f16 hi/lo split)
    for (int u = t; u < 512; u += 256) {
        int ulane = u & 63, nt = u >> 7, ks = (u >> 6) & 1;
        int n = nt*16 + (ulane & 15);
        int kbase = ks*32 + ((ulane >> 4) * 8);
        int fh = (((nt*2+ks)*2+0)*64 + ulane)*8;
        int fl = (((nt*2+ks)*2+1)*64 + ulane)*8;
        #pragma unroll
        for (int j = 0; j < 8; ++j) {
            int k = kbase + j;
            float vd = w1[k*64+n] - w1[4096 + k*64+n];
            _Float16 dh = (_Float16)vd;
            wdf[fh+j] = dh;
            wdf[fl+j] = (_Float16)(vd - (float)dh);
            float v2 = w2[k*64+n];
            _Float16 h2 = (_Float16)v2;
            w2f[fh+j] = h2;
            w2f[fl+j] = (_Float16)(v2 - (float)h2);
        }
    }
    __syncthreads();
    int lane = t & 63, wid = t >> 6;
    int m16 = lane & 15, gid = lane >> 4;
    int koct = gid*8, crow = gid*4;
    int i0 = blockIdx.x*64 + wid*16;          // first node of this wave
    int b  = blockIdx.x >> 4;                 // 16 blocks per graph
    const float* Ab = A + (size_t)b*M_*H_;

    // W2 B-frags -> registers (16 x half8 = 64 VGPR)
    half8 W2r[4][2][2];
    #pragma unroll
    for (int nt = 0; nt < 4; ++nt)
        #pragma unroll
        for (int ks = 0; ks < 2; ++ks)
            #pragma unroll
            for (int p = 0; p < 2; ++p)
                W2r[nt][ks][p] = *(const half8*)&w2f[(((nt*2+ks)*2+p)*64+lane)*8];

    float b1v[4];
    #pragma unroll
    for (int nt = 0; nt < 4; ++nt) b1v[nt] = b1[nt*16+m16];
    float b2v = b2[gid*16+m16];

    // ---- Phase 1: C tile = h(16 nodes) @ Wd + b1 ----
    half8 Hh[2], Hl[2];
    #pragma unroll
    for (int ks = 0; ks < 2; ++ks) {
        const float* hp = h + (size_t)(i0+m16)*64 + ks*32 + koct;
        float4 v0 = *(const float4*)hp;
        float4 v1 = *(const float4*)(hp+4);
        float va[8] = {v0.x,v0.y,v0.z,v0.w,v1.x,v1.y,v1.z,v1.w};
        #pragma unroll
        for (int j = 0; j < 8; ++j) {
            _Float16 hi = (_Float16)va[j];
            Hh[ks][j] = hi;
            Hl[ks][j] = (_Float16)(va[j]-(float)hi);
        }
    }
    #pragma unroll
    for (int nt = 0; nt < 4; ++nt) {
        floatx4 acc = {b1v[nt], b1v[nt], b1v[nt], b1v[nt]};
        #pragma unroll
        for (int ks = 0; ks < 2; ++ks) {
            half8 wh = *(const half8*)&wdf[(((nt*2+ks)*2+0)*64+lane)*8];
            half8 wl = *(const half8*)&wdf[(((nt*2+ks)*2+1)*64+lane)*8];
            acc = MFMA16(Hh[ks], wh, acc);
            acc = MFMA16(Hh[ks], wl, acc);
            acc = MFMA16(Hl[ks], wh, acc);
        }
        #pragma unroll
        for (int r = 0; r < 4; ++r) Cs[wid][crow+r][nt*16+m16] = acc[r];
    }
    __syncthreads();   // publish Cs (also orders ds_write->ds_read within wave)

    // ---- Phase 2: per node, msg = relu(C + A_j), out = max_e msg@W2 + b2 ----
    const unsigned short* knb = knn + (size_t)i0*16;
    #pragma unroll 2
    for (int nn = 0; nn < 16; ++nn) {
        int j = knb[nn*16 + m16];            // edge m16's neighbor (local id)
        const float* Ap = Ab + (size_t)j*64;
        half8 Mh[2], Ml[2];
        #pragma unroll
        for (int ks = 0; ks < 2; ++ks) {
            float4 a0 = *(const float4*)(Ap + ks*32 + koct);
            float4 a1 = *(const float4*)(Ap + ks*32 + koct + 4);
            const float* cp = &Cs[wid][nn][ks*32+koct];
            float4 c0 = *(const float4*)cp;
            float4 c1 = *(const float4*)(cp+4);
            float mv[8] = {
                fmaxf(a0.x+c0.x,0.f), fmaxf(a0.y+c0.y,0.f),
                fmaxf(a0.z+c0.z,0.f), fmaxf(a0.w+c0.w,0.f),
                fmaxf(a1.x+c1.x,0.f), fmaxf(a1.y+c1.y,0.f),
                fmaxf(a1.z+c1.z,0.f), fmaxf(a1.w+c1.w,0.f)};
            #pragma unroll
            for (int jj = 0; jj < 8; ++jj) {
                _Float16 hi = (_Float16)mv[jj];
                Mh[ks][jj] = hi;
                Ml[ks][jj] = (_Float16)(mv[jj]-(float)hi);
            }
        }
        floatx4 acc[4];
        #pragma unroll
        for (int nt = 0; nt < 4; ++nt) {
            acc[nt] = (floatx4){0.f,0.f,0.f,0.f};
            #pragma unroll
            for (int ks = 0; ks < 2; ++ks) {
                acc[nt] = MFMA16(Mh[ks], W2r[nt][ks][0], acc[nt]);
                acc[nt] = MFMA16(Mh[ks], W2r[nt][ks][1], acc[nt]);
                acc[nt] = MFMA16(Ml[ks], W2r[nt][ks][0], acc[nt]);
            }
        }
        // max over 16 edge rows: 4 regs then across the 4 lane-groups
        float om[4];
        #pragma unroll
        for (int nt = 0; nt < 4; ++nt) {
            float mr = fmaxf(fmaxf(acc[nt][0], acc[nt][1]),
                             fmaxf(acc[nt][2], acc[nt][3]));
            mr = fmaxf(mr, __shfl_xor(mr, 16, 64));
            mr = fmaxf(mr, __shfl_xor(mr, 32, 64));
            om[nt] = mr;
        }
        float val = (gid == 0) ? om[0] : (gid == 1) ? om[1]
                  : (gid == 2) ? om[2] : om[3];
        hout[(size_t)(i0+nn)*64 + gid*16 + m16] = val + b2v;
    }
}

// ---------------- mean-pool + output MLP ----------------
__global__ __launch_bounds__(256) void pool_kernel(
    const float* __restrict__ h,    // [N,64]
    const float* __restrict__ w1,   // [64,32]
    const float* __restrict__ b1,   // [32]
    const float* __restrict__ w2,   // [32,1]
    const float* __restrict__ b2,   // [1]
    float* __restrict__ out)        // [B]
{
    __shared__ float part[4][64];
    __shared__ float g[64];
    __shared__ float hid[32];
    int t = threadIdx.x;
    int o = t & 63, p = t >> 6;
    int b = blockIdx.x;
    const float* hb = h + (size_t)b*M_*H_;
    float s = 0.f;
    for (int m = p; m < M_; m += 4) s += hb[(size_t)m*64 + o];
    part[p][o] = s;
    __syncthreads();
    if (t < 64) g[t] = (part[0][t] + part[1][t] + part[2][t] + part[3][t]) * (1.f/M_);
    __syncthreads();
    if (t < 32) {
        float a = b1[t];
        for (int f = 0; f < 64; ++f) a += g[f] * w1[f*32 + t];
        hid[t] = fmaxf(a, 0.f);
    }
    __syncthreads();
    if (t == 0) {
        float a = b2[0];
        for (int f = 0; f < 32; ++f) a += hid[f] * w2[f];
        out[b] = a;
    }
}

extern "C" void kernel_launch(void* const* d_in, const int* in_sizes, int n_in,
                              void* d_out, int out_size, void* d_ws, size_t ws_size,
                              hipStream_t stream)
{
    (void)in_sizes; (void)n_in; (void)out_size; (void)ws_size;
    const float* x      = (const float*)d_in[0];
    const float* enc_w1 = (const float*)d_in[2];
    const float* enc_b1 = (const float*)d_in[3];
    const float* enc_w2 = (const float*)d_in[4];
    const float* enc_b2 = (const float*)d_in[5];
    const float* ec1_w1 = (const float*)d_in[6];
    const float* ec1_b1 = (const float*)d_in[7];
    const float* ec1_w2 = (const float*)d_in[8];
    const float* ec1_b2 = (const float*)d_in[9];
    const float* ec2_w1 = (const float*)d_in[10];
    const float* ec2_b1 = (const float*)d_in[11];
    const float* ec2_w2 = (const float*)d_in[12];
    const float* ec2_b2 = (const float*)d_in[13];
    const float* out_w1 = (const float*)d_in[14];
    const float* out_b1 = (const float*)d_in[15];
    const float* out_w2 = (const float*)d_in[16];
    const float* out_b2 = (const float*)d_in[17];

    // ws layout, 34.25 MB total. Region2 (16 MB) time-shared:
    //   (hhi|hlo) live producer->knn;  A lives gemmA->edge.  Never overlap.
    char* ws = (char*)d_ws;
    float*          h   = (float*)(ws);                                  // 16 MB
    char*           r2  = ws + (size_t)N_*64*4;                          // 16 MB
    _Float16*       hhi = (_Float16*)r2;                                 //  8 MB
    _Float16*       hlo = (_Float16*)(r2 + (size_t)N_*64*2);             //  8 MB
    float*          A   = (float*)r2;                                    // 16 MB (alias)
    unsigned short* idx = (unsigned short*)(ws + (size_t)N_*64*4*2);     //  2 MB
    float*          sq  = (float*)(ws + (size_t)N_*64*4*2 + (size_t)N_*16*2); // 256 KB

    enc_kernel<<<N_/256, 256, 0, stream>>>(x, enc_w1, enc_b1, enc_w2, enc_b2,
                                           h, hhi, hlo, sq);
    // layer 1
    knn_kernel <<<B_*16, 256, 0, stream>>>(hhi, hlo, sq, idx);
    gemmA_kernel<<<N_/256, 256, 0, stream>>>(h, ec1_w1, A);   // clobbers hhi/hlo (dead)
    edge_kernel<<<N_/64, 256, 0, stream>>>(h, A, idx, ec1_w1, ec1_b1, ec1_w2, ec1_b2, h);
    // layer 2
    convert_kernel<<<N_/64, 256, 0, stream>>>(h, hhi, hlo, sq); // clobbers A (dead)
    knn_kernel <<<B_*16, 256, 0, stream>>>(hhi, hlo, sq, idx);
    gemmA_kernel<<<N_/256, 256, 0, stream>>>(h, ec2_w1, A);
    edge_kernel<<<N_/64, 256, 0, stream>>>(h, A, idx, ec2_w1, ec2_b1, ec2_w2, ec2_b2, h);
    // pool + output MLP
    pool_kernel<<<B_, 256, 0, stream>>>(h, out_w1, out_b1, out_w2, out_b2, (float*)d_out);
}

// Round 9
// 587.135 us; speedup vs baseline: 9.7924x; 1.0261x over previous
//
#include <hip/hip_runtime.h>
#include <math.h>

#define B_ 64
#define M_ 1024
#define H_ 64
#define N_ (B_*M_)   // 65536

typedef _Float16 half8 __attribute__((ext_vector_type(8)));
typedef float  floatx4 __attribute__((ext_vector_type(4)));

#define MFMA16(a,b,c) __builtin_amdgcn_mfma_f32_16x16x32_f16(a,b,c,0,0,0)
#define MED3(a,b,c)   __builtin_amdgcn_fmed3f(a,b,c)

// ---------------- encoder: h = relu(relu(x@w1+b1)@w2+b2) (+ f16 split + sq) ------
__global__ __launch_bounds__(256) void enc_kernel(
    const float* __restrict__ x,     // [N,4]
    const float* __restrict__ w1,    // [4,32]
    const float* __restrict__ b1,    // [32]
    const float* __restrict__ w2,    // [32,64]
    const float* __restrict__ b2,    // [64]
    float* __restrict__ h,           // [N,64]
    _Float16* __restrict__ hhi,      // [N,64]
    _Float16* __restrict__ hlo,      // [N,64]
    float* __restrict__ sq)          // [N]
{
    __shared__ float sw1[4*32];
    __shared__ float sb1[32];
    __shared__ float sw2[32*64];
    __shared__ float sb2[64];
    int t = threadIdx.x;
    for (int i = t; i < 128; i += 256) sw1[i] = w1[i];
    if (t < 32) sb1[t] = b1[t];
    for (int i = t; i < 2048; i += 256) sw2[i] = w2[i];
    if (t < 64) sb2[t] = b2[t];
    __syncthreads();
    int n = blockIdx.x * 256 + t;
    float4 xv = *(const float4*)(x + (size_t)n*4);
    float hid[32];
    #pragma unroll
    for (int o = 0; o < 32; ++o) {
        float a = sb1[o] + xv.x*sw1[0*32+o] + xv.y*sw1[1*32+o]
                        + xv.z*sw1[2*32+o] + xv.w*sw1[3*32+o];
        hid[o] = fmaxf(a, 0.f);
    }
    float* hout = h + (size_t)n*64;
    float sqa = 0.f;
    #pragma unroll 4
    for (int oc = 0; oc < 16; ++oc) {
        float4 acc = make_float4(sb2[oc*4+0], sb2[oc*4+1], sb2[oc*4+2], sb2[oc*4+3]);
        #pragma unroll
        for (int f = 0; f < 32; ++f) {
            float4 w = *(const float4*)(sw2 + f*64 + oc*4);
            float hv = hid[f];
            acc.x += hv*w.x; acc.y += hv*w.y; acc.z += hv*w.z; acc.w += hv*w.w;
        }
        acc.x = fmaxf(acc.x,0.f); acc.y = fmaxf(acc.y,0.f);
        acc.z = fmaxf(acc.z,0.f); acc.w = fmaxf(acc.w,0.f);
        *(float4*)(hout + oc*4) = acc;
        sqa += acc.x*acc.x + acc.y*acc.y + acc.z*acc.z + acc.w*acc.w;
        union { _Float16 f[4]; uint2 u; } Hh, Hl;
        Hh.f[0]=(_Float16)acc.x; Hh.f[1]=(_Float16)acc.y;
        Hh.f[2]=(_Float16)acc.z; Hh.f[3]=(_Float16)acc.w;
        Hl.f[0]=(_Float16)(acc.x-(float)Hh.f[0]); Hl.f[1]=(_Float16)(acc.y-(float)Hh.f[1]);
        Hl.f[2]=(_Float16)(acc.z-(float)Hh.f[2]); Hl.f[3]=(_Float16)(acc.w-(float)Hh.f[3]);
        *(uint2*)(hhi + (size_t)n*64 + oc*4) = Hh.u;
        *(uint2*)(hlo + (size_t)n*64 + oc*4) = Hl.u;
    }
    sq[n] = sqa;
}

// ---------------- convert: h -> (hhi, hlo, sq)  (after edge layer 1) -------------
__global__ __launch_bounds__(256) void convert_kernel(
    const float* __restrict__ h,
    _Float16* __restrict__ hhi, _Float16* __restrict__ hlo,
    float* __restrict__ sq)
{
    int t = threadIdx.x, lane = t & 63, w = t >> 6;
    int base = blockIdx.x * 64 + w * 16;
    for (int it = 0; it < 16; ++it) {
        int i = base + it;
        float v = h[(size_t)i*64 + lane];
        _Float16 hi = (_Float16)v;
        _Float16 lo = (_Float16)(v - (float)hi);
        hhi[(size_t)i*64 + lane] = hi;
        hlo[(size_t)i*64 + lane] = lo;
        float s = v*v;
        #pragma unroll
        for (int off = 1; off < 64; off <<= 1) s += __shfl_xor(s, off, 64);
        if (lane == 0) sq[i] = s;
    }
}

// ---------------- A = h @ W1b  (W1b = rows 64..127 of w1) ----------------
__global__ __launch_bounds__(256) void gemmA_kernel(
    const float* __restrict__ h,
    const float* __restrict__ w1,   // [128,64]
    float* __restrict__ A)
{
    __shared__ float sw[64*64];
    int t = threadIdx.x;
    for (int idx = t; idx < 4096; idx += 256) sw[idx] = w1[4096 + idx];
    __syncthreads();
    int n = blockIdx.x * 256 + t;
    float4 hv[16];
    const float* src = h + (size_t)n*64;
    #pragma unroll
    for (int c = 0; c < 16; ++c) hv[c] = *(const float4*)(src + c*4);
    float* dst = A + (size_t)n*64;
    #pragma unroll 2
    for (int oc = 0; oc < 16; ++oc) {
        float4 acc = make_float4(0.f,0.f,0.f,0.f);
        #pragma unroll
        for (int f = 0; f < 64; ++f) {
            float xv = ((const float*)hv)[f];
            float4 w = *(const float4*)(sw + f*64 + oc*4);
            acc.x += xv*w.x; acc.y += xv*w.y; acc.z += xv*w.z; acc.w += xv*w.w;
        }
        *(float4*)(dst + oc*4) = acc;
    }
}

// ---------------- kNN v7: v6 + batched LDS reads in scan/merge (latency fix) -----
__global__ __launch_bounds__(256) void knn_kernel(
    const _Float16* __restrict__ hhi,
    const _Float16* __restrict__ hlo,
    const float* __restrict__ sqg,
    unsigned short* __restrict__ knn)    // [N,16]
{
    __shared__ float D[4][64*33];         // per-wave 64q x 32c tile, stride 33 (33.8 KB)
    __shared__ float sqS[1024];           // staged sq for the whole graph's 1024 nodes
    __shared__ unsigned int cntL[64], cntE[64];
    __shared__ unsigned short eqbuf[64][16];
    int t = threadIdx.x, lane = t & 63, w = t >> 6;
    int bi = blockIdx.x;
    int g  = (bi & 7) | ((bi >> 7) << 3);  // 16 blocks/graph share bi%8 -> same XCD L2
    int qt = (bi >> 3) & 15;
    const _Float16* hhig = hhi + (size_t)g*M_*64;
    const _Float16* hlog = hlo + (size_t)g*M_*64;
    const float*    sqb  = sqg + (size_t)g*M_;
    if (t < 64) { cntL[t] = 0; cntE[t] = 0; }
    ((float4*)sqS)[t] = ((const float4*)sqb)[t];   // 256 threads x 16B = 4 KB

    int m16  = lane & 15;
    int koct = (lane >> 4) * 8;
    half8 Ahi[4][2], Alo[4][2];
    #pragma unroll
    for (int rb = 0; rb < 4; ++rb) {
        const _Float16* ph = hhig + (size_t)(qt*64 + rb*16 + m16)*64;
        const _Float16* pl = hlog + (size_t)(qt*64 + rb*16 + m16)*64;
        Ahi[rb][0] = *(const half8*)(ph + koct);
        Ahi[rb][1] = *(const half8*)(ph + 32 + koct);
        Alo[rb][0] = *(const half8*)(pl + koct);
        Alo[rb][1] = *(const half8*)(pl + 32 + koct);
    }
    float* Dw   = D[w];
    int    crow = (lane >> 4) * 4;   // C/D: col=lane&15, row=(lane>>4)*4+reg
    float  bd[16];
    #pragma unroll
    for (int k = 0; k < 16; ++k) bd[k] = INFINITY;
    float tau = 0.f;
    size_t gq = (size_t)g*M_ + qt*64 + lane;
    int cand0 = w*256;               // this wave's candidate range base
    __syncthreads();                 // sqS ready

    for (int pass = 0; pass < 2; ++pass) {
        #pragma unroll
        for (int cc = 0; cc < 8; ++cc) {      // 8 chunks of 32 candidates (static!)
            int cbase = cand0 + cc*32;
            half8 Bhi[2][2], Blo[2][2];
            #pragma unroll
            for (int cb = 0; cb < 2; ++cb) {
                const _Float16* ph = hhig + (size_t)(cbase + cb*16 + m16)*64;
                const _Float16* pl = hlog + (size_t)(cbase + cb*16 + m16)*64;
                Bhi[cb][0] = *(const half8*)(ph + koct);
                Bhi[cb][1] = *(const half8*)(ph + 32 + koct);
                Blo[cb][0] = *(const half8*)(pl + koct);
                Blo[cb][1] = *(const half8*)(pl + 32 + koct);
            }
            #pragma unroll
            for (int rb = 0; rb < 4; ++rb) {
                #pragma unroll
                for (int cb = 0; cb < 2; ++cb) {
                    floatx4 acc = {0.f, 0.f, 0.f, 0.f};
                    acc = MFMA16(Ahi[rb][0], Bhi[cb][0], acc);
                    acc = MFMA16(Ahi[rb][1], Bhi[cb][1], acc);
                    acc = MFMA16(Ahi[rb][0], Blo[cb][0], acc);
                    acc = MFMA16(Ahi[rb][1], Blo[cb][1], acc);
                    acc = MFMA16(Alo[rb][0], Bhi[cb][0], acc);
                    acc = MFMA16(Alo[rb][1], Bhi[cb][1], acc);
                    #pragma unroll
                    for (int r = 0; r < 4; ++r)
                        Dw[(rb*16 + crow + r)*33 + cb*16 + m16] = acc[r];
                }
            }
            const float* drow = Dw + lane*33;
            int selfc = qt*64 + lane - cbase;    // in [0,32) iff self in this chunk
            if (pass == 0) {
                #pragma unroll
                for (int c8 = 0; c8 < 4; ++c8) {
                    float sv[8], qv[8];          // batch loads: 1 waitcnt per 8
                    #pragma unroll
                    for (int j = 0; j < 8; ++j) {
                        sv[j] = drow[c8*8 + j];
                        qv[j] = sqS[cbase + c8*8 + j];
                    }
                    #pragma unroll
                    for (int j = 0; j < 8; ++j) {
                        int c = c8*8 + j;
                        float s = fmaf(-2.f, sv[j], qv[j]);
                        if (c == selfc) s = INFINITY;
                        float nb0 = fminf(bd[0], s);
                        #pragma unroll
                        for (int k = 15; k >= 1; --k) bd[k] = MED3(s, bd[k-1], bd[k]);
                        bd[0] = nb0;
                    }
                }
            } else {
                #pragma unroll
                for (int c8 = 0; c8 < 4; ++c8) {
                    float sv[8], qv[8];
                    #pragma unroll
                    for (int j = 0; j < 8; ++j) {
                        sv[j] = drow[c8*8 + j];
                        qv[j] = sqS[cbase + c8*8 + j];
                    }
                    #pragma unroll
                    for (int j = 0; j < 8; ++j) {
                        int c = c8*8 + j;
                        float s = fmaf(-2.f, sv[j], qv[j]);
                        if (c == selfc) s = INFINITY;
                        if (s < tau) {
                            unsigned p = atomicAdd(&cntL[lane], 1u);
                            if (p < 16u) knn[gq*16 + p] = (unsigned short)(cbase + c);
                        } else if (s == tau) {
                            unsigned p = atomicAdd(&cntE[lane], 1u);
                            if (p < 16u) eqbuf[lane][p] = (unsigned short)(cbase + c);
                        }
                    }
                }
            }
        }
        if (pass == 0) {
            __syncthreads();                 // all waves done with their D tiles
            float* md = &D[0][0];            // alias as md[64][65]
            #pragma unroll
            for (int k = 0; k < 16; ++k) md[lane*65 + w*16 + k] = bd[k];
            __syncthreads();
            float b2[16];
            #pragma unroll
            for (int k = 0; k < 16; ++k) b2[k] = INFINITY;
            const float* mrow = md + lane*65;
            #pragma unroll
            for (int c8 = 0; c8 < 8; ++c8) {
                float sv[8];
                #pragma unroll
                for (int j = 0; j < 8; ++j) sv[j] = mrow[c8*8 + j];
                #pragma unroll
                for (int j = 0; j < 8; ++j) {
                    float s = sv[j];
                    float nb0 = fminf(b2[0], s);
                    #pragma unroll
                    for (int k = 15; k >= 1; --k) b2[k] = MED3(s, b2[k-1], b2[k]);
                    b2[0] = nb0;
                }
            }
            tau = b2[15];
            __syncthreads();                 // release md before pass-1 overwrites D
        }
    }
    __syncthreads();
    if (t < 64) {
        unsigned cL = cntL[t]; if (cL > 16u) cL = 16u;
        for (unsigned k = cL; k < 16u; ++k)
            knn[((size_t)g*M_ + qt*64 + t)*16 + k] = eqbuf[t][k - cL];
    }
}

// ---------------- EdgeConv v2 (MFMA): out_i = max_e ReLU(C_i + A_j)@W2 + b2 ------
__global__ __launch_bounds__(256) void edge_kernel(
    const float* __restrict__ h,     // [N,64] (in-place out OK: own rows read first)
    const float* __restrict__ A,     // [N,64]
    const unsigned short* __restrict__ knn, // [N,16] local idx
    const float* __restrict__ w1,    // [128,64]
    const float* __restrict__ b1,    // [64]
    const float* __restrict__ w2,    // [64,64]
    const float* __restrict__ b2,    // [64]
    float* __restrict__ hout)
{
    __shared__ _Float16 wdf[16*64*8];   // Wd B-frags pre-swizzled (16 KB)
    __shared__ _Float16 w2f[16*64*8];   // W2 B-frags pre-swizzled (16 KB)
    __shared__ float Cs[4][16][68];     // per-wave C tile (17.4 KB)
    int t = threadIdx.x;
    for (int u = t; u < 512; u += 256) {
        int ulane = u & 63, nt = u >> 7, ks = (u >> 6) & 1;
        int n = nt*16 + (ulane & 15);
        int kbase = ks*32 + ((ulane >> 4) * 8);
        int fh = (((nt*2+ks)*2+0)*64 + ulane)*8;
        int fl = (((nt*2+ks)*2+1)*64 + ulane)*8;
        #pragma unroll
        for (int j = 0; j < 8; ++j) {
            int k = kbase + j;
            float vd = w1[k*64+n] - w1[4096 + k*64+n];
            _Float16 dh = (_Float16)vd;
            wdf[fh+j] = dh;
            wdf[fl+j] = (_Float16)(vd - (float)dh);
            float v2 = w2[k*64+n];
            _Float16 h2 = (_Float16)v2;
            w2f[fh+j] = h2;
            w2f[fl+j] = (_Float16)(v2 - (float)h2);
        }
    }
    __syncthreads();
    int lane = t & 63, wid = t >> 6;
    int m16 = lane & 15, gid = lane >> 4;
    int koct = gid*8, crow = gid*4;
    int i0 = blockIdx.x*64 + wid*16;          // first node of this wave
    int b  = blockIdx.x >> 4;                 // 16 blocks per graph
    const float* Ab = A + (size_t)b*M_*H_;

    half8 W2r[4][2][2];
    #pragma unroll
    for (int nt = 0; nt < 4; ++nt)
        #pragma unroll
        for (int ks = 0; ks < 2; ++ks)
            #pragma unroll
            for (int p = 0; p < 2; ++p)
                W2r[nt][ks][p] = *(const half8*)&w2f[(((nt*2+ks)*2+p)*64+lane)*8];

    float b1v[4];
    #pragma unroll
    for (int nt = 0; nt < 4; ++nt) b1v[nt] = b1[nt*16+m16];
    float b2v = b2[gid*16+m16];

    // ---- Phase 1: C tile = h(16 nodes) @ Wd + b1 ----
    half8 Hh[2], Hl[2];
    #pragma unroll
    for (int ks = 0; ks < 2; ++ks) {
        const float* hp = h + (size_t)(i0+m16)*64 + ks*32 + koct;
        float4 v0 = *(const float4*)hp;
        float4 v1 = *(const float4*)(hp+4);
        float va[8] = {v0.x,v0.y,v0.z,v0.w,v1.x,v1.y,v1.z,v1.w};
        #pragma unroll
        for (int j = 0; j < 8; ++j) {
            _Float16 hi = (_Float16)va[j];
            Hh[ks][j] = hi;
            Hl[ks][j] = (_Float16)(va[j]-(float)hi);
        }
    }
    #pragma unroll
    for (int nt = 0; nt < 4; ++nt) {
        floatx4 acc = {b1v[nt], b1v[nt], b1v[nt], b1v[nt]};
        #pragma unroll
        for (int ks = 0; ks < 2; ++ks) {
            half8 wh = *(const half8*)&wdf[(((nt*2+ks)*2+0)*64+lane)*8];
            half8 wl = *(const half8*)&wdf[(((nt*2+ks)*2+1)*64+lane)*8];
            acc = MFMA16(Hh[ks], wh, acc);
            acc = MFMA16(Hh[ks], wl, acc);
            acc = MFMA16(Hl[ks], wh, acc);
        }
        #pragma unroll
        for (int r = 0; r < 4; ++r) Cs[wid][crow+r][nt*16+m16] = acc[r];
    }
    __syncthreads();

    // ---- Phase 2: per node, msg = relu(C + A_j), out = max_e msg@W2 + b2 ----
    const unsigned short* knb = knn + (size_t)i0*16;
    #pragma unroll 2
    for (int nn = 0; nn < 16; ++nn) {
        int j = knb[nn*16 + m16];
        const float* Ap = Ab + (size_t)j*64;
        half8 Mh[2], Ml[2];
        #pragma unroll
        for (int ks = 0; ks < 2; ++ks) {
            float4 a0 = *(const float4*)(Ap + ks*32 + koct);
            float4 a1 = *(const float4*)(Ap + ks*32 + koct + 4);
            const float* cp = &Cs[wid][nn][ks*32+koct];
            float4 c0 = *(const float4*)cp;
            float4 c1 = *(const float4*)(cp+4);
            float mv[8] = {
                fmaxf(a0.x+c0.x,0.f), fmaxf(a0.y+c0.y,0.f),
                fmaxf(a0.z+c0.z,0.f), fmaxf(a0.w+c0.w,0.f),
                fmaxf(a1.x+c1.x,0.f), fmaxf(a1.y+c1.y,0.f),
                fmaxf(a1.z+c1.z,0.f), fmaxf(a1.w+c1.w,0.f)};
            #pragma unroll
            for (int jj = 0; jj < 8; ++jj) {
                _Float16 hi = (_Float16)mv[jj];
                Mh[ks][jj] = hi;
                Ml[ks][jj] = (_Float16)(mv[jj]-(float)hi);
            }
        }
        floatx4 acc[4];
        #pragma unroll
        for (int nt = 0; nt < 4; ++nt) {
            acc[nt] = (floatx4){0.f,0.f,0.f,0.f};
            #pragma unroll
            for (int ks = 0; ks < 2; ++ks) {
                acc[nt] = MFMA16(Mh[ks], W2r[nt][ks][0], acc[nt]);
                acc[nt] = MFMA16(Mh[ks], W2r[nt][ks][1], acc[nt]);
                acc[nt] = MFMA16(Ml[ks], W2r[nt][ks][0], acc[nt]);
            }
        }
        float om[4];
        #pragma unroll
        for (int nt = 0; nt < 4; ++nt) {
            float mr = fmaxf(fmaxf(acc[nt][0], acc[nt][1]),
                             fmaxf(acc[nt][2], acc[nt][3]));
            mr = fmaxf(mr, __shfl_xor(mr, 16, 64));
            mr = fmaxf(mr, __shfl_xor(mr, 32, 64));
            om[nt] = mr;
        }
        float val = (gid == 0) ? om[0] : (gid == 1) ? om[1]
                  : (gid == 2) ? om[2] : om[3];
        hout[(size_t)(i0+nn)*64 + gid*16 + m16] = val + b2v;
    }
}

// ---------------- mean-pool + output MLP ----------------
__global__ __launch_bounds__(256) void pool_kernel(
    const float* __restrict__ h,    // [N,64]
    const float* __restrict__ w1,   // [64,32]
    const float* __restrict__ b1,   // [32]
    const float* __restrict__ w2,   // [32,1]
    const float* __restrict__ b2,   // [1]
    float* __restrict__ out)        // [B]
{
    __shared__ float part[4][64];
    __shared__ float g[64];
    __shared__ float hid[32];
    int t = threadIdx.x;
    int o = t & 63, p = t >> 6;
    int b = blockIdx.x;
    const float* hb = h + (size_t)b*M_*H_;
    float s = 0.f;
    for (int m = p; m < M_; m += 4) s += hb[(size_t)m*64 + o];
    part[p][o] = s;
    __syncthreads();
    if (t < 64) g[t] = (part[0][t] + part[1][t] + part[2][t] + part[3][t]) * (1.f/M_);
    __syncthreads();
    if (t < 32) {
        float a = b1[t];
        for (int f = 0; f < 64; ++f) a += g[f] * w1[f*32 + t];
        hid[t] = fmaxf(a, 0.f);
    }
    __syncthreads();
    if (t == 0) {
        float a = b2[0];
        for (int f = 0; f < 32; ++f) a += hid[f] * w2[f];
        out[b] = a;
    }
}

extern "C" void kernel_launch(void* const* d_in, const int* in_sizes, int n_in,
                              void* d_out, int out_size, void* d_ws, size_t ws_size,
                              hipStream_t stream)
{
    (void)in_sizes; (void)n_in; (void)out_size; (void)ws_size;
    const float* x      = (const float*)d_in[0];
    const float* enc_w1 = (const float*)d_in[2];
    const float* enc_b1 = (const float*)d_in[3];
    const float* enc_w2 = (const float*)d_in[4];
    const float* enc_b2 = (const float*)d_in[5];
    const float* ec1_w1 = (const float*)d_in[6];
    const float* ec1_b1 = (const float*)d_in[7];
    const float* ec1_w2 = (const float*)d_in[8];
    const float* ec1_b2 = (const float*)d_in[9];
    const float* ec2_w1 = (const float*)d_in[10];
    const float* ec2_b1 = (const float*)d_in[11];
    const float* ec2_w2 = (const float*)d_in[12];
    const float* ec2_b2 = (const float*)d_in[13];
    const float* out_w1 = (const float*)d_in[14];
    const float* out_b1 = (const float*)d_in[15];
    const float* out_w2 = (const float*)d_in[16];
    const float* out_b2 = (const float*)d_in[17];

    // ws layout, 34.25 MB total. Region2 (16 MB) time-shared:
    //   (hhi|hlo) live producer->knn;  A lives gemmA->edge.  Never overlap.
    char* ws = (char*)d_ws;
    float*          h   = (float*)(ws);                                  // 16 MB
    char*           r2  = ws + (size_t)N_*64*4;                          // 16 MB
    _Float16*       hhi = (_Float16*)r2;                                 //  8 MB
    _Float16*       hlo = (_Float16*)(r2 + (size_t)N_*64*2);             //  8 MB
    float*          A   = (float*)r2;                                    // 16 MB (alias)
    unsigned short* idx = (unsigned short*)(ws + (size_t)N_*64*4*2);     //  2 MB
    float*          sq  = (float*)(ws + (size_t)N_*64*4*2 + (size_t)N_*16*2); // 256 KB

    enc_kernel<<<N_/256, 256, 0, stream>>>(x, enc_w1, enc_b1, enc_w2, enc_b2,
                                           h, hhi, hlo, sq);
    // layer 1
    knn_kernel <<<B_*16, 256, 0, stream>>>(hhi, hlo, sq, idx);
    gemmA_kernel<<<N_/256, 256, 0, stream>>>(h, ec1_w1, A);   // clobbers hhi/hlo (dead)
    edge_kernel<<<N_/64, 256, 0, stream>>>(h, A, idx, ec1_w1, ec1_b1, ec1_w2, ec1_b2, h);
    // layer 2
    convert_kernel<<<N_/64, 256, 0, stream>>>(h, hhi, hlo, sq); // clobbers A (dead)
    knn_kernel <<<B_*16, 256, 0, stream>>>(hhi, hlo, sq, idx);
    gemmA_kernel<<<N_/256, 256, 0, stream>>>(h, ec2_w1, A);
    edge_kernel<<<N_/64, 256, 0, stream>>>(h, A, idx, ec2_w1, ec2_b1, ec2_w2, ec2_b2, h);
    // pool + output MLP
    pool_kernel<<<B_, 256, 0, stream>>>(h, out_w1, out_b1, out_w2, out_b2, (float*)d_out);
}

// Round 10
// 420.681 us; speedup vs baseline: 13.6671x; 1.3957x over previous
//
#include <hip/hip_runtime.h>
#include <math.h>

#define B_ 64
#define M_ 1024
#define H_ 64
#define N_ (B_*M_)   // 65536

typedef _Float16 half8 __attribute__((ext_vector_type(8)));
typedef float  floatx4 __attribute__((ext_vector_type(4)));

#define MFMA16(a,b,c) __builtin_amdgcn_mfma_f32_16x16x32_f16(a,b,c,0,0,0)
#define MED3(a,b,c)   __builtin_amdgcn_fmed3f(a,b,c)

// ---------------- encoder: h = relu(relu(x@w1+b1)@w2+b2) (+ f16 split + sq) ------
__global__ __launch_bounds__(256) void enc_kernel(
    const float* __restrict__ x,     // [N,4]
    const float* __restrict__ w1,    // [4,32]
    const float* __restrict__ b1,    // [32]
    const float* __restrict__ w2,    // [32,64]
    const float* __restrict__ b2,    // [64]
    float* __restrict__ h,           // [N,64]
    _Float16* __restrict__ hhi,      // [N,64]
    _Float16* __restrict__ hlo,      // [N,64]
    float* __restrict__ sq)          // [N]
{
    __shared__ float sw1[4*32];
    __shared__ float sb1[32];
    __shared__ float sw2[32*64];
    __shared__ float sb2[64];
    int t = threadIdx.x;
    for (int i = t; i < 128; i += 256) sw1[i] = w1[i];
    if (t < 32) sb1[t] = b1[t];
    for (int i = t; i < 2048; i += 256) sw2[i] = w2[i];
    if (t < 64) sb2[t] = b2[t];
    __syncthreads();
    int n = blockIdx.x * 256 + t;
    float4 xv = *(const float4*)(x + (size_t)n*4);
    float hid[32];
    #pragma unroll
    for (int o = 0; o < 32; ++o) {
        float a = sb1[o] + xv.x*sw1[0*32+o] + xv.y*sw1[1*32+o]
                        + xv.z*sw1[2*32+o] + xv.w*sw1[3*32+o];
        hid[o] = fmaxf(a, 0.f);
    }
    float* hout = h + (size_t)n*64;
    float sqa = 0.f;
    #pragma unroll 4
    for (int oc = 0; oc < 16; ++oc) {
        float4 acc = make_float4(sb2[oc*4+0], sb2[oc*4+1], sb2[oc*4+2], sb2[oc*4+3]);
        #pragma unroll
        for (int f = 0; f < 32; ++f) {
            float4 w = *(const float4*)(sw2 + f*64 + oc*4);
            float hv = hid[f];
            acc.x += hv*w.x; acc.y += hv*w.y; acc.z += hv*w.z; acc.w += hv*w.w;
        }
        acc.x = fmaxf(acc.x,0.f); acc.y = fmaxf(acc.y,0.f);
        acc.z = fmaxf(acc.z,0.f); acc.w = fmaxf(acc.w,0.f);
        *(float4*)(hout + oc*4) = acc;
        sqa += acc.x*acc.x + acc.y*acc.y + acc.z*acc.z + acc.w*acc.w;
        union { _Float16 f[4]; uint2 u; } Hh, Hl;
        Hh.f[0]=(_Float16)acc.x; Hh.f[1]=(_Float16)acc.y;
        Hh.f[2]=(_Float16)acc.z; Hh.f[3]=(_Float16)acc.w;
        Hl.f[0]=(_Float16)(acc.x-(float)Hh.f[0]); Hl.f[1]=(_Float16)(acc.y-(float)Hh.f[1]);
        Hl.f[2]=(_Float16)(acc.z-(float)Hh.f[2]); Hl.f[3]=(_Float16)(acc.w-(float)Hh.f[3]);
        *(uint2*)(hhi + (size_t)n*64 + oc*4) = Hh.u;
        *(uint2*)(hlo + (size_t)n*64 + oc*4) = Hl.u;
    }
    sq[n] = sqa;
}

// ---------------- convert: h -> (hhi, hlo, sq)  (after edge layer 1) -------------
__global__ __launch_bounds__(256) void convert_kernel(
    const float* __restrict__ h,
    _Float16* __restrict__ hhi, _Float16* __restrict__ hlo,
    float* __restrict__ sq)
{
    int t = threadIdx.x, lane = t & 63, w = t >> 6;
    int base = blockIdx.x * 64 + w * 16;
    for (int it = 0; it < 16; ++it) {
        int i = base + it;
        float v = h[(size_t)i*64 + lane];
        _Float16 hi = (_Float16)v;
        _Float16 lo = (_Float16)(v - (float)hi);
        hhi[(size_t)i*64 + lane] = hi;
        hlo[(size_t)i*64 + lane] = lo;
        float s = v*v;
        #pragma unroll
        for (int off = 1; off < 64; off <<= 1) s += __shfl_xor(s, off, 64);
        if (lane == 0) sq[i] = s;
    }
}

// ---------------- A = h @ W1b  (W1b = rows 64..127 of w1) ----------------
__global__ __launch_bounds__(256) void gemmA_kernel(
    const float* __restrict__ h,
    const float* __restrict__ w1,   // [128,64]
    float* __restrict__ A)
{
    __shared__ float sw[64*64];
    int t = threadIdx.x;
    for (int idx = t; idx < 4096; idx += 256) sw[idx] = w1[4096 + idx];
    __syncthreads();
    int n = blockIdx.x * 256 + t;
    float4 hv[16];
    const float* src = h + (size_t)n*64;
    #pragma unroll
    for (int c = 0; c < 16; ++c) hv[c] = *(const float4*)(src + c*4);
    float* dst = A + (size_t)n*64;
    #pragma unroll 2
    for (int oc = 0; oc < 16; ++oc) {
        float4 acc = make_float4(0.f,0.f,0.f,0.f);
        #pragma unroll
        for (int f = 0; f < 64; ++f) {
            float xv = ((const float*)hv)[f];
            float4 w = *(const float4*)(sw + f*64 + oc*4);
            acc.x += xv*w.x; acc.y += xv*w.y; acc.z += xv*w.z; acc.w += xv*w.w;
        }
        *(float4*)(dst + oc*4) = acc;
    }
}

// ---------------- kNN v8: SINGLE PASS with packed sort keys ----------------
// key = float( bits(1 + d^2) & ~1023 | cand_idx )  -- positive finite, distinct;
// float order == (quantized d^2, idx) lex order == top_k tie rule.
// med3 network keeps top-16 keys; merge (wave 0) extracts indices directly.
__global__ __launch_bounds__(256) void knn_kernel(
    const _Float16* __restrict__ hhi,
    const _Float16* __restrict__ hlo,
    const float* __restrict__ sqg,
    unsigned short* __restrict__ knn)    // [N,16]
{
    __shared__ float D[4][64*33];         // per-wave 64q x 32c tile, stride 33 (33.8 KB)
    __shared__ float sqS[1024];           // staged sq for the graph's 1024 nodes
    int t = threadIdx.x, lane = t & 63, w = t >> 6;
    int bi = blockIdx.x;
    int g  = (bi & 7) | ((bi >> 7) << 3);  // 16 blocks/graph share bi%8 -> same XCD L2
    int qt = (bi >> 3) & 15;
    const _Float16* hhig = hhi + (size_t)g*M_*64;
    const _Float16* hlog = hlo + (size_t)g*M_*64;
    const float*    sqb  = sqg + (size_t)g*M_;
    ((float4*)sqS)[t] = ((const float4*)sqb)[t];   // 256 threads x 16B = 4 KB

    int m16  = lane & 15;
    int koct = (lane >> 4) * 8;
    half8 Ahi[4][2], Alo[4][2];
    #pragma unroll
    for (int rb = 0; rb < 4; ++rb) {
        const _Float16* ph = hhig + (size_t)(qt*64 + rb*16 + m16)*64;
        const _Float16* pl = hlog + (size_t)(qt*64 + rb*16 + m16)*64;
        Ahi[rb][0] = *(const half8*)(ph + koct);
        Ahi[rb][1] = *(const half8*)(ph + 32 + koct);
        Alo[rb][0] = *(const half8*)(pl + koct);
        Alo[rb][1] = *(const half8*)(pl + 32 + koct);
    }
    float* Dw   = D[w];
    int    crow = (lane >> 4) * 4;   // C/D: col=lane&15, row=(lane>>4)*4+reg
    float  bd[16];
    #pragma unroll
    for (int k = 0; k < 16; ++k) bd[k] = INFINITY;
    int cand0 = w*256;               // this wave's candidate range base
    __syncthreads();                 // sqS ready
    float c1 = 1.f + sqS[qt*64 + lane];   // 1 + sq_i (query constant)
    int selfc_all = qt*64 + lane;

    #pragma unroll
    for (int cc = 0; cc < 8; ++cc) {      // 8 chunks of 32 candidates (static!)
        int cbase = cand0 + cc*32;
        half8 Bhi[2][2], Blo[2][2];
        #pragma unroll
        for (int cb = 0; cb < 2; ++cb) {
            const _Float16* ph = hhig + (size_t)(cbase + cb*16 + m16)*64;
            const _Float16* pl = hlog + (size_t)(cbase + cb*16 + m16)*64;
            Bhi[cb][0] = *(const half8*)(ph + koct);
            Bhi[cb][1] = *(const half8*)(ph + 32 + koct);
            Blo[cb][0] = *(const half8*)(pl + koct);
            Blo[cb][1] = *(const half8*)(pl + 32 + koct);
        }
        #pragma unroll
        for (int rb = 0; rb < 4; ++rb) {
            #pragma unroll
            for (int cb = 0; cb < 2; ++cb) {
                floatx4 acc = {0.f, 0.f, 0.f, 0.f};
                acc = MFMA16(Ahi[rb][0], Bhi[cb][0], acc);
                acc = MFMA16(Ahi[rb][1], Bhi[cb][1], acc);
                acc = MFMA16(Ahi[rb][0], Blo[cb][0], acc);
                acc = MFMA16(Ahi[rb][1], Blo[cb][1], acc);
                acc = MFMA16(Alo[rb][0], Bhi[cb][0], acc);
                acc = MFMA16(Alo[rb][1], Bhi[cb][1], acc);
                #pragma unroll
                for (int r = 0; r < 4; ++r)
                    Dw[(rb*16 + crow + r)*33 + cb*16 + m16] = acc[r];
            }
        }
        const float* drow = Dw + lane*33;
        int selfc = selfc_all - cbase;       // in [0,32) iff self in this chunk
        #pragma unroll
        for (int c8 = 0; c8 < 4; ++c8) {
            float sv[8], qv[8];              // batch loads: 1 waitcnt per 8
            #pragma unroll
            for (int j = 0; j < 8; ++j) {
                sv[j] = drow[c8*8 + j];
                qv[j] = sqS[cbase + c8*8 + j];
            }
            #pragma unroll
            for (int j = 0; j < 8; ++j) {
                int c = c8*8 + j;
                float s  = fmaf(-2.f, sv[j], qv[j]);     // sq_j - 2 dot
                float t2 = c1 + s;                       // 1 + d^2  (>0)
                unsigned kb = (__float_as_uint(t2) & 0xFFFFFC00u)
                            | (unsigned)(cbase + c);
                float fk = __uint_as_float(kb);
                if (c == selfc) fk = INFINITY;
                float nb0 = fminf(bd[0], fk);
                #pragma unroll
                for (int k = 15; k >= 1; --k) bd[k] = MED3(fk, bd[k-1], bd[k]);
                bd[0] = nb0;
            }
        }
    }

    // ---- merge 4 per-wave sorted key lists; wave 0 extracts indices ----
    __syncthreads();                 // all waves done with their D tiles
    float* md = &D[0][0];            // alias as md[64][65]
    #pragma unroll
    for (int k = 0; k < 16; ++k) md[lane*65 + w*16 + k] = bd[k];
    __syncthreads();
    if (w == 0) {
        float b2[16];
        #pragma unroll
        for (int k = 0; k < 16; ++k) b2[k] = INFINITY;
        const float* mrow = md + lane*65;
        #pragma unroll
        for (int c8 = 0; c8 < 8; ++c8) {
            float sv[8];
            #pragma unroll
            for (int j = 0; j < 8; ++j) sv[j] = mrow[c8*8 + j];
            #pragma unroll
            for (int j = 0; j < 8; ++j) {
                float s = sv[j];
                float nb0 = fminf(b2[0], s);
                #pragma unroll
                for (int k = 15; k >= 1; --k) b2[k] = MED3(s, b2[k-1], b2[k]);
                b2[0] = nb0;
            }
        }
        union { unsigned short us[16]; uint4 v4[2]; } o;
        #pragma unroll
        for (int k = 0; k < 16; ++k)
            o.us[k] = (unsigned short)(__float_as_uint(b2[k]) & 1023u);
        size_t gq = (size_t)g*M_ + qt*64 + lane;
        uint4* dst = (uint4*)(knn + gq*16);
        dst[0] = o.v4[0];
        dst[1] = o.v4[1];
    }
}

// ---------------- EdgeConv v3 (MFMA): Cs aliased onto w2f, XCD swizzle ----------
__global__ __launch_bounds__(256) void edge_kernel(
    const float* __restrict__ h,     // [N,64] (in-place out OK: own rows read first)
    const float* __restrict__ A,     // [N,64]
    const unsigned short* __restrict__ knn, // [N,16] local idx
    const float* __restrict__ w1,    // [128,64]
    const float* __restrict__ b1,    // [64]
    const float* __restrict__ w2,    // [64,64]
    const float* __restrict__ b2,    // [64]
    float* __restrict__ hout)
{
    __shared__ __align__(16) _Float16 wdf[16*64*8];   // Wd B-frags (16 KB)
    __shared__ __align__(16) _Float16 w2f[16*64*8];   // W2 B-frags (16 KB) -> Cs after
    float* CsB = (float*)w2f;                          // Cs[4][16][64] alias (16 KB)
    int t = threadIdx.x;
    for (int u = t; u < 512; u += 256) {
        int ulane = u & 63, nt = u >> 7, ks = (u >> 6) & 1;
        int n = nt*16 + (ulane & 15);
        int kbase = ks*32 + ((ulane >> 4) * 8);
        int fh = (((nt*2+ks)*2+0)*64 + ulane)*8;
        int fl = (((nt*2+ks)*2+1)*64 + ulane)*8;
        #pragma unroll
        for (int j = 0; j < 8; ++j) {
            int k = kbase + j;
            float vd = w1[k*64+n] - w1[4096 + k*64+n];
            _Float16 dh = (_Float16)vd;
            wdf[fh+j] = dh;
            wdf[fl+j] = (_Float16)(vd - (float)dh);
            float v2 = w2[k*64+n];
            _Float16 h2 = (_Float16)v2;
            w2f[fh+j] = h2;
            w2f[fl+j] = (_Float16)(v2 - (float)h2);
        }
    }
    __syncthreads();
    int lane = t & 63, wid = t >> 6;
    int m16 = lane & 15, gid = lane >> 4;
    int koct = gid*8, crow = gid*4;
    int bi = blockIdx.x;
    int g  = (bi & 7) | ((bi >> 7) << 3);    // XCD swizzle: graph's blocks share an XCD
    int qt = (bi >> 3) & 15;
    int i0 = g*M_ + qt*64 + wid*16;          // first node of this wave
    const float* Ab = A + (size_t)g*M_*H_;

    half8 W2r[4][2][2];
    #pragma unroll
    for (int nt = 0; nt < 4; ++nt)
        #pragma unroll
        for (int ks = 0; ks < 2; ++ks)
            #pragma unroll
            for (int p = 0; p < 2; ++p)
                W2r[nt][ks][p] = *(const half8*)&w2f[(((nt*2+ks)*2+p)*64+lane)*8];

    float b1v[4];
    #pragma unroll
    for (int nt = 0; nt < 4; ++nt) b1v[nt] = b1[nt*16+m16];
    float b2v = b2[gid*16+m16];
    __syncthreads();   // all waves done reading w2f -> safe to overwrite with Cs

    // ---- Phase 1: C tile = h(16 nodes) @ Wd + b1 -> CsB (over w2f) ----
    half8 Hh[2], Hl[2];
    #pragma unroll
    for (int ks = 0; ks < 2; ++ks) {
        const float* hp = h + (size_t)(i0+m16)*64 + ks*32 + koct;
        float4 v0 = *(const float4*)hp;
        float4 v1 = *(const float4*)(hp+4);
        float va[8] = {v0.x,v0.y,v0.z,v0.w,v1.x,v1.y,v1.z,v1.w};
        #pragma unroll
        for (int j = 0; j < 8; ++j) {
            _Float16 hi = (_Float16)va[j];
            Hh[ks][j] = hi;
            Hl[ks][j] = (_Float16)(va[j]-(float)hi);
        }
    }
    #pragma unroll
    for (int nt = 0; nt < 4; ++nt) {
        floatx4 acc = {b1v[nt], b1v[nt], b1v[nt], b1v[nt]};
        #pragma unroll
        for (int ks = 0; ks < 2; ++ks) {
            half8 wh = *(const half8*)&wdf[(((nt*2+ks)*2+0)*64+lane)*8];
            half8 wl = *(const half8*)&wdf[(((nt*2+ks)*2+1)*64+lane)*8];
            acc = MFMA16(Hh[ks], wh, acc);
            acc = MFMA16(Hh[ks], wl, acc);
            acc = MFMA16(Hl[ks], wh, acc);
        }
        #pragma unroll
        for (int r = 0; r < 4; ++r)
            CsB[((wid*16) + crow + r)*64 + nt*16 + m16] = acc[r];
    }
    __syncthreads();

    // ---- Phase 2: per node, msg = relu(C + A_j), out = max_e msg@W2 + b2 ----
    const unsigned short* knb = knn + (size_t)i0*16;
    #pragma unroll 2
    for (int nn = 0; nn < 16; ++nn) {
        int j = knb[nn*16 + m16];
        const float* Ap = Ab + (size_t)j*64;
        half8 Mh[2], Ml[2];
        #pragma unroll
        for (int ks = 0; ks < 2; ++ks) {
            float4 a0 = *(const float4*)(Ap + ks*32 + koct);
            float4 a1 = *(const float4*)(Ap + ks*32 + koct + 4);
            const float* cp = &CsB[(wid*16 + nn)*64 + ks*32 + koct];
            float4 c0 = *(const float4*)cp;
            float4 c1 = *(const float4*)(cp+4);
            float mv[8] = {
                fmaxf(a0.x+c0.x,0.f), fmaxf(a0.y+c0.y,0.f),
                fmaxf(a0.z+c0.z,0.f), fmaxf(a0.w+c0.w,0.f),
                fmaxf(a1.x+c1.x,0.f), fmaxf(a1.y+c1.y,0.f),
                fmaxf(a1.z+c1.z,0.f), fmaxf(a1.w+c1.w,0.f)};
            #pragma unroll
            for (int jj = 0; jj < 8; ++jj) {
                _Float16 hi = (_Float16)mv[jj];
                Mh[ks][jj] = hi;
                Ml[ks][jj] = (_Float16)(mv[jj]-(float)hi);
            }
        }
        floatx4 acc[4];
        #pragma unroll
        for (int nt = 0; nt < 4; ++nt) {
            acc[nt] = (floatx4){0.f,0.f,0.f,0.f};
            #pragma unroll
            for (int ks = 0; ks < 2; ++ks) {
                acc[nt] = MFMA16(Mh[ks], W2r[nt][ks][0], acc[nt]);
                acc[nt] = MFMA16(Mh[ks], W2r[nt][ks][1], acc[nt]);
                acc[nt] = MFMA16(Ml[ks], W2r[nt][ks][0], acc[nt]);
            }
        }
        float om[4];
        #pragma unroll
        for (int nt = 0; nt < 4; ++nt) {
            float mr = fmaxf(fmaxf(acc[nt][0], acc[nt][1]),
                             fmaxf(acc[nt][2], acc[nt][3]));
            mr = fmaxf(mr, __shfl_xor(mr, 16, 64));
            mr = fmaxf(mr, __shfl_xor(mr, 32, 64));
            om[nt] = mr;
        }
        float val = (gid == 0) ? om[0] : (gid == 1) ? om[1]
                  : (gid == 2) ? om[2] : om[3];
        hout[(size_t)(i0+nn)*64 + gid*16 + m16] = val + b2v;
    }
}

// ---------------- mean-pool + output MLP ----------------
__global__ __launch_bounds__(256) void pool_kernel(
    const float* __restrict__ h,    // [N,64]
    const float* __restrict__ w1,   // [64,32]
    const float* __restrict__ b1,   // [32]
    const float* __restrict__ w2,   // [32,1]
    const float* __restrict__ b2,   // [1]
    float* __restrict__ out)        // [B]
{
    __shared__ float part[4][64];
    __shared__ float g[64];
    __shared__ float hid[32];
    int t = threadIdx.x;
    int o = t & 63, p = t >> 6;
    int b = blockIdx.x;
    const float* hb = h + (size_t)b*M_*H_;
    float s = 0.f;
    for (int m = p; m < M_; m += 4) s += hb[(size_t)m*64 + o];
    part[p][o] = s;
    __syncthreads();
    if (t < 64) g[t] = (part[0][t] + part[1][t] + part[2][t] + part[3][t]) * (1.f/M_);
    __syncthreads();
    if (t < 32) {
        float a = b1[t];
        for (int f = 0; f < 64; ++f) a += g[f] * w1[f*32 + t];
        hid[t] = fmaxf(a, 0.f);
    }
    __syncthreads();
    if (t == 0) {
        float a = b2[0];
        for (int f = 0; f < 32; ++f) a += hid[f] * w2[f];
        out[b] = a;
    }
}

extern "C" void kernel_launch(void* const* d_in, const int* in_sizes, int n_in,
                              void* d_out, int out_size, void* d_ws, size_t ws_size,
                              hipStream_t stream)
{
    (void)in_sizes; (void)n_in; (void)out_size; (void)ws_size;
    const float* x      = (const float*)d_in[0];
    const float* enc_w1 = (const float*)d_in[2];
    const float* enc_b1 = (const float*)d_in[3];
    const float* enc_w2 = (const float*)d_in[4];
    const float* enc_b2 = (const float*)d_in[5];
    const float* ec1_w1 = (const float*)d_in[6];
    const float* ec1_b1 = (const float*)d_in[7];
    const float* ec1_w2 = (const float*)d_in[8];
    const float* ec1_b2 = (const float*)d_in[9];
    const float* ec2_w1 = (const float*)d_in[10];
    const float* ec2_b1 = (const float*)d_in[11];
    const float* ec2_w2 = (const float*)d_in[12];
    const float* ec2_b2 = (const float*)d_in[13];
    const float* out_w1 = (const float*)d_in[14];
    const float* out_b1 = (const float*)d_in[15];
    const float* out_w2 = (const float*)d_in[16];
    const float* out_b2 = (const float*)d_in[17];

    // ws layout, 34.25 MB total. Region2 (16 MB) time-shared:
    //   (hhi|hlo) live producer->knn;  A lives gemmA->edge.  Never overlap.
    char* ws = (char*)d_ws;
    float*          h   = (float*)(ws);                                  // 16 MB
    char*           r2  = ws + (size_t)N_*64*4;                          // 16 MB
    _Float16*       hhi = (_Float16*)r2;                                 //  8 MB
    _Float16*       hlo = (_Float16*)(r2 + (size_t)N_*64*2);             //  8 MB
    float*          A   = (float*)r2;                                    // 16 MB (alias)
    unsigned short* idx = (unsigned short*)(ws + (size_t)N_*64*4*2);     //  2 MB
    float*          sq  = (float*)(ws + (size_t)N_*64*4*2 + (size_t)N_*16*2); // 256 KB

    enc_kernel<<<N_/256, 256, 0, stream>>>(x, enc_w1, enc_b1, enc_w2, enc_b2,
                                           h, hhi, hlo, sq);
    // layer 1
    knn_kernel <<<B_*16, 256, 0, stream>>>(hhi, hlo, sq, idx);
    gemmA_kernel<<<N_/256, 256, 0, stream>>>(h, ec1_w1, A);   // clobbers hhi/hlo (dead)
    edge_kernel<<<N_/64, 256, 0, stream>>>(h, A, idx, ec1_w1, ec1_b1, ec1_w2, ec1_b2, h);
    // layer 2
    convert_kernel<<<N_/64, 256, 0, stream>>>(h, hhi, hlo, sq); // clobbers A (dead)
    knn_kernel <<<B_*16, 256, 0, stream>>>(hhi, hlo, sq, idx);
    gemmA_kernel<<<N_/256, 256, 0, stream>>>(h, ec2_w1, A);
    edge_kernel<<<N_/64, 256, 0, stream>>>(h, A, idx, ec2_w1, ec2_b1, ec2_w2, ec2_b2, h);
    // pool + output MLP
    pool_kernel<<<B_, 256, 0, stream>>>(h, out_w1, out_b1, out_w2, out_b2, (float*)d_out);
}